// Round 2
// baseline (5493.298 us; speedup 1.0000x reference)
//
#include <hip/hip_runtime.h>
#include <hip/hip_bf16.h>
#include <math.h>

#define B_ 8
#define S_ 1024
#define F_ 75
#define D_ 128
#define INNER_ 256
#define NH_ 4
#define DH_ 64
#define MROWS_ (B_*S_)   // 8192

static __device__ __forceinline__ float sigm(float x){ return 1.0f/(1.0f+expf(-x)); }
static __device__ __forceinline__ float logsig(float x){
    return (x >= 0.f) ? -log1pf(expf(-x)) : (x - log1pf(expf(x)));
}

// ---------------- Generic tiled GEMM: C = A @ W^T + bias (+ res) ----------------
// A: (M,K) row-major fp32, W: (N,K) row-major fp32, bias: (N,) fp32
__global__ void gemm_bias(const float* __restrict__ A, const float* __restrict__ W,
                          const float* __restrict__ bias, const float* __restrict__ res,
                          float* __restrict__ C, int M, int N, int K) {
    __shared__ float As[32][17];
    __shared__ float Ws[32][17];
    int tx = threadIdx.x, ty = threadIdx.y;   // 16x16
    int tid = ty*16 + tx;
    int m0 = blockIdx.y*32, n0 = blockIdx.x*32;
    float acc00=0.f, acc01=0.f, acc10=0.f, acc11=0.f;
    int r = tid >> 3;           // 0..31
    int cc = (tid & 7) * 2;     // 0..14
    for (int k0 = 0; k0 < K; k0 += 16) {
        int ka = k0 + cc;
        As[r][cc]   = (ka   < K) ? A[(size_t)(m0+r)*K + ka]   : 0.f;
        As[r][cc+1] = (ka+1 < K) ? A[(size_t)(m0+r)*K + ka+1] : 0.f;
        Ws[r][cc]   = (ka   < K) ? W[(size_t)(n0+r)*K + ka]   : 0.f;
        Ws[r][cc+1] = (ka+1 < K) ? W[(size_t)(n0+r)*K + ka+1] : 0.f;
        __syncthreads();
        #pragma unroll
        for (int kk = 0; kk < 16; ++kk) {
            float a0 = As[ty*2][kk],   a1 = As[ty*2+1][kk];
            float b0 = Ws[tx*2][kk],   b1 = Ws[tx*2+1][kk];
            acc00 += a0*b0; acc01 += a0*b1; acc10 += a1*b0; acc11 += a1*b1;
        }
        __syncthreads();
    }
    int m = m0 + ty*2, n = n0 + tx*2;
    float bs0 = bias[n], bs1 = bias[n+1];
    float v00 = acc00+bs0, v01 = acc01+bs1, v10 = acc10+bs0, v11 = acc11+bs1;
    if (res) {
        v00 += res[(size_t)m*N+n];     v01 += res[(size_t)m*N+n+1];
        v10 += res[(size_t)(m+1)*N+n]; v11 += res[(size_t)(m+1)*N+n+1];
    }
    C[(size_t)m*N+n]     = v00; C[(size_t)m*N+n+1]     = v01;
    C[(size_t)(m+1)*N+n] = v10; C[(size_t)(m+1)*N+n+1] = v11;
}

// ---------------- Plain LayerNorm over D=128 ----------------
__global__ void ln_kernel(const float* __restrict__ X, const float* __restrict__ w,
                          float* __restrict__ Y) {
    int row = blockIdx.x, t = threadIdx.x;  // 128 threads
    float v = X[(size_t)row*128 + t];
    __shared__ float s1[128], s2[128];
    s1[t]=v; s2[t]=v*v; __syncthreads();
    for (int off=64; off>0; off>>=1){
        if (t<off){ s1[t]+=s1[t+off]; s2[t]+=s2[t+off]; }
        __syncthreads();
    }
    float mu = s1[0]*(1.f/128.f);
    float var = s2[0]*(1.f/128.f) - mu*mu;
    Y[(size_t)row*128 + t] = (v-mu)*rsqrtf(var+1e-5f)*w[t];
}

// ---------------- Causal depthwise conv (K=4) + SiLU ----------------
__global__ void conv_silu(const float* __restrict__ X, int ldx,
                          const float* __restrict__ kw, const float* __restrict__ kb,
                          float* __restrict__ Y, int ldy, int C) {
    int idx = blockIdx.x*blockDim.x + threadIdx.x;
    int total = MROWS_*C;
    if (idx >= total) return;
    int c = idx % C; int bs = idx / C;
    int s = bs % S_; int b = bs / S_;
    float acc = kb[c];
    #pragma unroll
    for (int i = 0; i < 4; ++i) {
        int sp = s - 3 + i;
        if (sp >= 0) acc += X[((size_t)b*S_+sp)*ldx + c] * kw[c*4+i];
    }
    Y[((size_t)b*S_+s)*ldy + c] = acc * sigm(acc);
}

// ---------------- Headwise block-diagonal proj (mLSTM q/k/v, HS=4) ----------------
__global__ void headwise4(const float* __restrict__ X, int ldx,
                          const float* __restrict__ W, const float* __restrict__ bias,
                          float* __restrict__ Y) {
    int idx = blockIdx.x*blockDim.x + threadIdx.x;
    int total = MROWS_*INNER_;
    if (idx >= total) return;
    int co = idx % INNER_; int bs = idx / INNER_;
    int h = co >> 2, o = co & 3;
    const float* Wh = W + ((size_t)h*4 + o)*4;
    const float* xr = X + (size_t)bs*ldx + h*4;
    float acc = bias[co];
    #pragma unroll
    for (int i = 0; i < 4; ++i) acc += xr[i]*Wh[i];
    Y[(size_t)bs*INNER_ + co] = acc;
}

// ---------------- sLSTM headwise (HS=32) writing into gx slot g ----------------
__global__ void headwise_gate(const float* __restrict__ X, const float* __restrict__ W,
                              float* __restrict__ GX, int g) {
    int idx = blockIdx.x*blockDim.x + threadIdx.x;
    int total = MROWS_*128;
    if (idx >= total) return;
    int co = idx % 128; int bs = idx / 128;
    int h = co >> 5, o = co & 31;
    const float* Wh = W + ((size_t)h*32 + o)*32;
    const float* xr = X + (size_t)bs*128 + h*32;
    float acc = 0.f;
    #pragma unroll
    for (int i = 0; i < 32; ++i) acc += xr[i]*Wh[i];
    GX[(size_t)bs*512 + h*128 + g*32 + o] = acc;
}

// ---------------- ig/fg gate projection over concat(q,k,v) ----------------
__global__ void gateproj(const float* __restrict__ q, const float* __restrict__ k,
                         const float* __restrict__ v,
                         const float* __restrict__ Wig, const float* __restrict__ big,
                         const float* __restrict__ Wfg, const float* __restrict__ bfg,
                         float* __restrict__ igp, float* __restrict__ fgp) {
    int bs = blockIdx.x; int lane = threadIdx.x;  // 64 threads
    int b = bs / S_, s = bs % S_;
    const float* qr = q + (size_t)bs*INNER_;
    const float* kr = k + (size_t)bs*INNER_;
    const float* vr = v + (size_t)bs*INNER_;
    float dots[8];
    #pragma unroll
    for (int g=0; g<8; ++g) dots[g]=0.f;
    for (int c = lane; c < INNER_; c += 64) {
        float qv = qr[c], kv = kr[c], vv = vr[c];
        #pragma unroll
        for (int g=0; g<4; ++g) {
            dots[g]   += qv*Wig[g*768+c] + kv*Wig[g*768+256+c] + vv*Wig[g*768+512+c];
            dots[4+g] += qv*Wfg[g*768+c] + kv*Wfg[g*768+256+c] + vv*Wfg[g*768+512+c];
        }
    }
    #pragma unroll
    for (int off=32; off>0; off>>=1)
        #pragma unroll
        for (int g=0; g<8; ++g) dots[g] += __shfl_down(dots[g], off, 64);
    if (lane == 0) {
        #pragma unroll
        for (int g=0; g<4; ++g) {
            igp[((size_t)b*NH_+g)*S_ + s] = dots[g]   + big[g];
            fgp[((size_t)b*NH_+g)*S_ + s] = dots[4+g] + bfg[g];
        }
    }
}

// ---------------- mLSTM decay precompute: lc, a = ig - lc, prefix-max(a) ----------------
__global__ void mlstm_scan_pre(const float* __restrict__ igp, const float* __restrict__ fgp,
                               float* __restrict__ lc, float* __restrict__ av,
                               float* __restrict__ mx) {
    int bh = blockIdx.x; int t = threadIdx.x;  // 1024 threads
    __shared__ float buf[2][1024];
    float ls = logsig(fgp[(size_t)bh*S_ + t]);
    int cur = 0;
    buf[0][t] = ls; __syncthreads();
    for (int off=1; off<1024; off<<=1) {
        float x2 = buf[cur][t];
        if (t >= off) x2 += buf[cur][t-off];
        buf[cur^1][t] = x2; cur ^= 1; __syncthreads();
    }
    float lcv = buf[cur][t];
    lc[(size_t)bh*S_+t] = lcv;
    float a = igp[(size_t)bh*S_+t] - lcv;
    av[(size_t)bh*S_+t] = a;
    __syncthreads();
    cur = 0; buf[0][t] = a; __syncthreads();
    for (int off=1; off<1024; off<<=1) {
        float x2 = buf[cur][t];
        if (t >= off) x2 = fmaxf(x2, buf[cur][t-off]);
        buf[cur^1][t] = x2; cur ^= 1; __syncthreads();
    }
    mx[(size_t)bh*S_+t] = buf[cur][t];
}

// ---------------- mLSTM attention: one wave per output row ----------------
__global__ __launch_bounds__(64) void mlstm_attn(
        const float* __restrict__ q, const float* __restrict__ k,
        const float* __restrict__ v, const float* __restrict__ lc,
        const float* __restrict__ av, const float* __restrict__ mx,
        float* __restrict__ hc) {
    int idx = blockIdx.x;
    int s = idx % S_; int bh = idx / S_;
    int hh = bh % NH_; int b = bh / NH_;
    int lane = threadIdx.x;
    __shared__ float qs[64];
    __shared__ float kt[64][65];
    __shared__ float vt[64][65];
    __shared__ float cb[64];
    qs[lane] = q[((size_t)b*S_ + s)*INNER_ + hh*64 + lane] * 0.125f;  // fold 1/sqrt(DH)
    float Ms = mx[(size_t)bh*S_ + s];
    float maxs = lc[(size_t)bh*S_ + s] + Ms;
    const float* av_bh = av + (size_t)bh*S_;
    float acc = 0.f, sumC = 0.f;
    for (int t0 = 0; t0 <= s; t0 += 64) {
        for (int r = 0; r < 64; ++r) {
            kt[r][lane] = k[((size_t)b*S_ + t0 + r)*INNER_ + hh*64 + lane];
            vt[r][lane] = v[((size_t)b*S_ + t0 + r)*INNER_ + hh*64 + lane];
        }
        __syncthreads();
        int t = t0 + lane;
        float Ct = 0.f;
        if (t <= s) {
            float dot = 0.f;
            #pragma unroll
            for (int d = 0; d < 64; ++d) dot += kt[lane][d]*qs[d];
            Ct = dot * expf(av_bh[t] - Ms);
        }
        sumC += Ct;
        cb[lane] = Ct;
        __syncthreads();
        int tmax = min(63, s - t0);
        for (int tt = 0; tt <= tmax; ++tt) acc += cb[tt]*vt[tt][lane];
        __syncthreads();
    }
    #pragma unroll
    for (int off=32; off>0; off>>=1) sumC += __shfl_down(sumC, off, 64);
    sumC = __shfl(sumC, 0, 64);
    float norm = fmaxf(fabsf(sumC), expf(-maxs)) + 1e-6f;
    hc[((size_t)b*S_ + s)*INNER_ + hh*64 + lane] = acc / norm;
}

// ---------------- mLSTM output: multihead LN (GS=64) + skip + gate ----------------
__global__ void mlstm_out(const float* __restrict__ hc, const float* __restrict__ xc,
                          const float* __restrict__ up, const float* __restrict__ onw,
                          const float* __restrict__ skip, float* __restrict__ hs) {
    int row = blockIdx.x; int c = threadIdx.x;  // 256 threads
    float v = hc[(size_t)row*INNER_ + c];
    __shared__ float s1[256], s2[256];
    s1[c]=v; s2[c]=v*v; __syncthreads();
    int li = c & 63;
    for (int off=32; off>0; off>>=1){
        if (li < off){ s1[c]+=s1[c+off]; s2[c]+=s2[c+off]; }
        __syncthreads();
    }
    int base = c & ~63;
    float mu = s1[base]*(1.f/64.f);
    float var = s2[base]*(1.f/64.f) - mu*mu;
    float ht = (v-mu)*rsqrtf(var+1e-5f)*onw[c];
    float z = up[(size_t)row*512 + 256 + c];
    hs[(size_t)row*INNER_ + c] = (ht + skip[c]*xc[(size_t)row*INNER_+c]) * (z*sigm(z));
}

// ---------------- sLSTM sequential scan: one block per (b,h) ----------------
__global__ __launch_bounds__(128) void slstm_scan(
        const float* __restrict__ gx, const float* __restrict__ R,
        const float* __restrict__ bb, float* __restrict__ ys) {
    int blk = blockIdx.x; int hh = blk & 3; int b = blk >> 2;
    int j = threadIdx.x;  // 128 threads: j = g*32+e
    __shared__ float RL[32*128];
    __shared__ float yL[32];
    __shared__ float rawL[128];
    for (int d = 0; d < 32; ++d)
        RL[d*128 + j] = R[(size_t)(hh*32 + d)*128 + j];
    float bj = bb[hh*128 + j];
    if (j < 32) yL[j] = 0.f;
    float cst = 0.f, nst = 0.f, mst = 0.f;
    __syncthreads();
    float gcur = gx[((size_t)(b*S_ + 0)*NH_ + hh)*128 + j];
    for (int t = 0; t < S_; ++t) {
        float gnext = (t+1 < S_) ? gx[((size_t)(b*S_ + t+1)*NH_ + hh)*128 + j] : 0.f;
        float raw = gcur + bj;
        #pragma unroll 8
        for (int d = 0; d < 32; ++d) raw += yL[d]*RL[d*128 + j];
        rawL[j] = raw; __syncthreads();
        if (j < 32) {
            float iraw = rawL[j], fraw = rawL[32+j], zraw = rawL[64+j], oraw = rawL[96+j];
            float lfm = mst + logsig(fraw);
            float mnew = (t == 0) ? iraw : fmaxf(iraw, lfm);
            float og = sigm(oraw);
            float igv = expf(iraw - mnew), fgv = expf(lfm - mnew);
            cst = fgv*cst + igv*tanhf(zraw);
            nst = fgv*nst + igv;
            mst = mnew;
            float y = og*cst/nst;
            yL[j] = y;
            ys[(size_t)(b*S_ + t)*128 + hh*32 + j] = y;
        }
        __syncthreads();
        gcur = gnext;
    }
}

// ---------------- sLSTM out: h += mh_ln(ys; GS=32) * gnw ----------------
__global__ void slstm_addnorm(const float* __restrict__ ys, const float* __restrict__ w,
                              float* __restrict__ h) {
    int row = blockIdx.x; int c = threadIdx.x;  // 128
    float v = ys[(size_t)row*128 + c];
    __shared__ float s1[128], s2[128];
    s1[c]=v; s2[c]=v*v; __syncthreads();
    int li = c & 31;
    for (int off=16; off>0; off>>=1){
        if (li < off){ s1[c]+=s1[c+off]; s2[c]+=s2[c+off]; }
        __syncthreads();
    }
    int base = c & ~31;
    float mu = s1[base]*(1.f/32.f);
    float var = s2[base]*(1.f/32.f) - mu*mu;
    h[(size_t)row*128 + c] += (v-mu)*rsqrtf(var+1e-5f)*w[c];
}

// ---------------- FFN activation: gelu(g) * u2 ----------------
__global__ void ffn_act(const float* __restrict__ u, float* __restrict__ act) {
    int idx = blockIdx.x*blockDim.x + threadIdx.x;
    int total = MROWS_*192;
    if (idx >= total) return;
    int j = idx % 192; int m = idx / 192;
    float g  = u[(size_t)m*384 + j];
    float u2 = u[(size_t)m*384 + 192 + j];
    float ge = 0.5f*g*(1.0f + erff(g*0.70710678118f));
    act[(size_t)m*192 + j] = ge*u2;
}

// ---------------- Final FC on last token ----------------
__global__ void final_fc(const float* __restrict__ hp, const float* __restrict__ fcW,
                         const float* __restrict__ fcb, float* __restrict__ out) {
    int b = blockIdx.x; int lane = threadIdx.x;  // 64
    const float* r = hp + ((size_t)b*S_ + (S_-1))*128;
    float acc = r[lane]*fcW[lane] + r[lane+64]*fcW[lane+64];
    #pragma unroll
    for (int off=32; off>0; off>>=1) acc += __shfl_down(acc, off, 64);
    if (lane == 0) out[b] = acc + fcb[0];
}

extern "C" void kernel_launch(void* const* d_in, const int* in_sizes, int n_in,
                              void* d_out, int out_size, void* d_ws, size_t ws_size,
                              hipStream_t stream) {
    const float* x       = (const float*)d_in[0];
    const float* W_in    = (const float*)d_in[1];
    const float* b_in    = (const float*)d_in[2];
    const float* ln0_w   = (const float*)d_in[3];
    const float* m_Wup   = (const float*)d_in[4];
    const float* m_bup   = (const float*)d_in[5];
    const float* m_convk = (const float*)d_in[6];
    const float* m_convb = (const float*)d_in[7];
    const float* m_Wq    = (const float*)d_in[8];
    const float* m_bq    = (const float*)d_in[9];
    const float* m_Wk    = (const float*)d_in[10];
    const float* m_bk    = (const float*)d_in[11];
    const float* m_Wv    = (const float*)d_in[12];
    const float* m_bv    = (const float*)d_in[13];
    const float* m_Wig   = (const float*)d_in[14];
    const float* m_big   = (const float*)d_in[15];
    const float* m_Wfg   = (const float*)d_in[16];
    const float* m_bfg   = (const float*)d_in[17];
    const float* m_onw   = (const float*)d_in[18];
    const float* m_skip  = (const float*)d_in[19];
    const float* m_Wd    = (const float*)d_in[20];
    const float* m_bd    = (const float*)d_in[21];
    const float* ln1_w   = (const float*)d_in[22];
    const float* s_convk = (const float*)d_in[23];
    const float* s_convb = (const float*)d_in[24];
    const float* s_Wi    = (const float*)d_in[25];
    const float* s_Wf    = (const float*)d_in[26];
    const float* s_Wz    = (const float*)d_in[27];
    const float* s_Wo    = (const float*)d_in[28];
    const float* s_R     = (const float*)d_in[29];
    const float* s_b     = (const float*)d_in[30];
    const float* s_gnw   = (const float*)d_in[31];
    const float* ffn_nw  = (const float*)d_in[32];
    const float* f_Wu    = (const float*)d_in[33];
    const float* f_bu    = (const float*)d_in[34];
    const float* f_Wd    = (const float*)d_in[35];
    const float* f_bd    = (const float*)d_in[36];
    const float* post_w  = (const float*)d_in[37];
    const float* fc_W    = (const float*)d_in[38];
    const float* fc_b    = (const float*)d_in[39];
    float* out = (float*)d_out;

    float* W = (float*)d_ws;
    const size_t M1 = 1048576;        // 8192*128
    float* h    = W;                   // 1M
    float* r    = W + 1*M1;            // 1M  (all LN outputs, incl. hp)
    float* up   = W + 2*M1;            // 4M  (xm = cols 0..255, z = cols 256..511); later u (3M)
    float* xc   = W + 6*M1;            // 2M  ; later rc (1M)
    float* q    = W + 8*M1;            // 2M  ; later hs, later act
    float* kbuf = W + 10*M1;           // 2M  \ later gx (4M)
    float* vbuf = W + 12*M1;           // 2M  /
    float* hc   = W + 14*M1;           // 2M  ; later ys (1M)
    float* igp  = W + 16*M1;           // 32K each
    float* fgp  = igp + 32768;
    float* lc   = fgp + 32768;
    float* av   = lc  + 32768;
    float* mx   = av  + 32768;
    float* hs   = q;
    float* gx   = kbuf;
    float* ys   = hc;
    float* rc   = xc;
    float* u    = up;
    float* act  = q;
    float* hp   = r;

    dim3 blk16(16,16);

    // 1. h = x @ W_in^T + b_in
    gemm_bias<<<dim3(128/32, MROWS_/32), blk16, 0, stream>>>(x, W_in, b_in, nullptr, h, MROWS_, 128, F_);
    // 2. r = LN(h)*ln0_w
    ln_kernel<<<MROWS_, 128, 0, stream>>>(h, ln0_w, r);
    // 3. up = r @ m_Wup^T + m_bup
    gemm_bias<<<dim3(512/32, MROWS_/32), blk16, 0, stream>>>(r, m_Wup, m_bup, nullptr, up, MROWS_, 512, 128);
    // 4. xc = silu(causal_conv(xm))
    conv_silu<<<(MROWS_*256)/256, 256, 0, stream>>>(up, 512, m_convk, m_convb, xc, 256, 256);
    // 5. q,k,v headwise
    headwise4<<<(MROWS_*256)/256, 256, 0, stream>>>(xc, 256, m_Wq, m_bq, q);
    headwise4<<<(MROWS_*256)/256, 256, 0, stream>>>(xc, 256, m_Wk, m_bk, kbuf);
    headwise4<<<(MROWS_*256)/256, 256, 0, stream>>>(up, 512, m_Wv, m_bv, vbuf);
    // 6. ig/fg projections
    gateproj<<<MROWS_, 64, 0, stream>>>(q, kbuf, vbuf, m_Wig, m_big, m_Wfg, m_bfg, igp, fgp);
    // 7. decay precompute
    mlstm_scan_pre<<<B_*NH_, 1024, 0, stream>>>(igp, fgp, lc, av, mx);
    // 8. attention
    mlstm_attn<<<B_*NH_*S_, 64, 0, stream>>>(q, kbuf, vbuf, lc, av, mx, hc);
    // 9. multihead LN + skip + gate
    mlstm_out<<<MROWS_, 256, 0, stream>>>(hc, xc, up, m_onw, m_skip, hs);
    // 10. h += hs @ m_Wd^T + m_bd
    gemm_bias<<<dim3(128/32, MROWS_/32), blk16, 0, stream>>>(hs, m_Wd, m_bd, h, h, MROWS_, 128, 256);
    // 11. r = LN(h)*ln1_w
    ln_kernel<<<MROWS_, 128, 0, stream>>>(h, ln1_w, r);
    // 12. rc = silu(causal_conv(r))
    conv_silu<<<(MROWS_*128)/256, 256, 0, stream>>>(r, 128, s_convk, s_convb, rc, 128, 128);
    // 13. sLSTM gates
    headwise_gate<<<(MROWS_*128)/256, 256, 0, stream>>>(rc, s_Wi, gx, 0);
    headwise_gate<<<(MROWS_*128)/256, 256, 0, stream>>>(rc, s_Wf, gx, 1);
    headwise_gate<<<(MROWS_*128)/256, 256, 0, stream>>>(r,  s_Wz, gx, 2);
    headwise_gate<<<(MROWS_*128)/256, 256, 0, stream>>>(r,  s_Wo, gx, 3);
    // 14. sequential scan
    slstm_scan<<<B_*NH_, 128, 0, stream>>>(gx, s_R, s_b, ys);
    // 15. h += mh_ln(ys)*s_gnw
    slstm_addnorm<<<MROWS_, 128, 0, stream>>>(ys, s_gnw, h);
    // 16. r = LN(h)*ffn_nw
    ln_kernel<<<MROWS_, 128, 0, stream>>>(h, ffn_nw, r);
    // 17. u = r @ f_Wu^T + f_bu
    gemm_bias<<<dim3(384/32, MROWS_/32), blk16, 0, stream>>>(r, f_Wu, f_bu, nullptr, u, MROWS_, 384, 128);
    // 18. act = gelu(g)*u2
    ffn_act<<<(MROWS_*192)/256, 256, 0, stream>>>(u, act);
    // 19. h += act @ f_Wd^T + f_bd
    gemm_bias<<<dim3(128/32, MROWS_/32), blk16, 0, stream>>>(act, f_Wd, f_bd, h, h, MROWS_, 128, 192);
    // 20. hp = LN(h)*post_w
    ln_kernel<<<MROWS_, 128, 0, stream>>>(h, post_w, hp);
    // 21. out = hp[:, -1, :] @ fc_W^T + fc_b
    final_fc<<<B_, 64, 0, stream>>>(hp, fc_W, fc_b, out);
    (void)in_sizes; (void)n_in; (void)out_size; (void)ws_size;
}

// Round 3
// 2798.244 us; speedup vs baseline: 1.9631x; 1.9631x over previous
//
#include <hip/hip_runtime.h>
#include <hip/hip_bf16.h>
#include <math.h>

#define B_ 8
#define S_ 1024
#define F_ 75
#define D_ 128
#define INNER_ 256
#define NH_ 4
#define DH_ 64
#define MROWS_ (B_*S_)   // 8192

static __device__ __forceinline__ float sigm(float x){ return 1.0f/(1.0f+expf(-x)); }
static __device__ __forceinline__ float logsig(float x){
    return (x >= 0.f) ? -log1pf(expf(-x)) : (x - log1pf(expf(x)));
}

// ---------------- Generic tiled GEMM: C = A @ W^T + bias (+ res) ----------------
__global__ void gemm_bias(const float* __restrict__ A, const float* __restrict__ W,
                          const float* __restrict__ bias, const float* __restrict__ res,
                          float* __restrict__ C, int M, int N, int K) {
    __shared__ float As[32][17];
    __shared__ float Ws[32][17];
    int tx = threadIdx.x, ty = threadIdx.y;   // 16x16
    int tid = ty*16 + tx;
    int m0 = blockIdx.y*32, n0 = blockIdx.x*32;
    float acc00=0.f, acc01=0.f, acc10=0.f, acc11=0.f;
    int r = tid >> 3;           // 0..31
    int cc = (tid & 7) * 2;     // 0..14
    for (int k0 = 0; k0 < K; k0 += 16) {
        int ka = k0 + cc;
        As[r][cc]   = (ka   < K) ? A[(size_t)(m0+r)*K + ka]   : 0.f;
        As[r][cc+1] = (ka+1 < K) ? A[(size_t)(m0+r)*K + ka+1] : 0.f;
        Ws[r][cc]   = (ka   < K) ? W[(size_t)(n0+r)*K + ka]   : 0.f;
        Ws[r][cc+1] = (ka+1 < K) ? W[(size_t)(n0+r)*K + ka+1] : 0.f;
        __syncthreads();
        #pragma unroll
        for (int kk = 0; kk < 16; ++kk) {
            float a0 = As[ty*2][kk],   a1 = As[ty*2+1][kk];
            float b0 = Ws[tx*2][kk],   b1 = Ws[tx*2+1][kk];
            acc00 += a0*b0; acc01 += a0*b1; acc10 += a1*b0; acc11 += a1*b1;
        }
        __syncthreads();
    }
    int m = m0 + ty*2, n = n0 + tx*2;
    float bs0 = bias[n], bs1 = bias[n+1];
    float v00 = acc00+bs0, v01 = acc01+bs1, v10 = acc10+bs0, v11 = acc11+bs1;
    if (res) {
        v00 += res[(size_t)m*N+n];     v01 += res[(size_t)m*N+n+1];
        v10 += res[(size_t)(m+1)*N+n]; v11 += res[(size_t)(m+1)*N+n+1];
    }
    C[(size_t)m*N+n]     = v00; C[(size_t)m*N+n+1]     = v01;
    C[(size_t)(m+1)*N+n] = v10; C[(size_t)(m+1)*N+n+1] = v11;
}

// ---------------- Plain LayerNorm over D=128 ----------------
__global__ void ln_kernel(const float* __restrict__ X, const float* __restrict__ w,
                          float* __restrict__ Y) {
    int row = blockIdx.x, t = threadIdx.x;  // 128 threads
    float v = X[(size_t)row*128 + t];
    __shared__ float s1[128], s2[128];
    s1[t]=v; s2[t]=v*v; __syncthreads();
    for (int off=64; off>0; off>>=1){
        if (t<off){ s1[t]+=s1[t+off]; s2[t]+=s2[t+off]; }
        __syncthreads();
    }
    float mu = s1[0]*(1.f/128.f);
    float var = s2[0]*(1.f/128.f) - mu*mu;
    Y[(size_t)row*128 + t] = (v-mu)*rsqrtf(var+1e-5f)*w[t];
}

// ---------------- Causal depthwise conv (K=4) + SiLU ----------------
__global__ void conv_silu(const float* __restrict__ X, int ldx,
                          const float* __restrict__ kw, const float* __restrict__ kb,
                          float* __restrict__ Y, int ldy, int C) {
    int idx = blockIdx.x*blockDim.x + threadIdx.x;
    int total = MROWS_*C;
    if (idx >= total) return;
    int c = idx % C; int bs = idx / C;
    int s = bs % S_; int b = bs / S_;
    float acc = kb[c];
    #pragma unroll
    for (int i = 0; i < 4; ++i) {
        int sp = s - 3 + i;
        if (sp >= 0) acc += X[((size_t)b*S_+sp)*ldx + c] * kw[c*4+i];
    }
    Y[((size_t)b*S_+s)*ldy + c] = acc * sigm(acc);
}

// ---------------- Headwise block-diagonal proj (mLSTM q/k/v, HS=4) ----------------
__global__ void headwise4(const float* __restrict__ X, int ldx,
                          const float* __restrict__ W, const float* __restrict__ bias,
                          float* __restrict__ Y) {
    int idx = blockIdx.x*blockDim.x + threadIdx.x;
    int total = MROWS_*INNER_;
    if (idx >= total) return;
    int co = idx % INNER_; int bs = idx / INNER_;
    int h = co >> 2, o = co & 3;
    const float* Wh = W + ((size_t)h*4 + o)*4;
    const float* xr = X + (size_t)bs*ldx + h*4;
    float acc = bias[co];
    #pragma unroll
    for (int i = 0; i < 4; ++i) acc += xr[i]*Wh[i];
    Y[(size_t)bs*INNER_ + co] = acc;
}

// ---------------- sLSTM headwise (HS=32) writing into gx slot g ----------------
__global__ void headwise_gate(const float* __restrict__ X, const float* __restrict__ W,
                              float* __restrict__ GX, int g) {
    int idx = blockIdx.x*blockDim.x + threadIdx.x;
    int total = MROWS_*128;
    if (idx >= total) return;
    int co = idx % 128; int bs = idx / 128;
    int h = co >> 5, o = co & 31;
    const float* Wh = W + ((size_t)h*32 + o)*32;
    const float* xr = X + (size_t)bs*128 + h*32;
    float acc = 0.f;
    #pragma unroll
    for (int i = 0; i < 32; ++i) acc += xr[i]*Wh[i];
    GX[(size_t)bs*512 + h*128 + g*32 + o] = acc;
}

// ---------------- ig/fg gate projection over concat(q,k,v) ----------------
__global__ void gateproj(const float* __restrict__ q, const float* __restrict__ k,
                         const float* __restrict__ v,
                         const float* __restrict__ Wig, const float* __restrict__ big,
                         const float* __restrict__ Wfg, const float* __restrict__ bfg,
                         float* __restrict__ igp, float* __restrict__ fgp) {
    int bs = blockIdx.x; int lane = threadIdx.x;  // 64 threads
    int b = bs / S_, s = bs % S_;
    const float* qr = q + (size_t)bs*INNER_;
    const float* kr = k + (size_t)bs*INNER_;
    const float* vr = v + (size_t)bs*INNER_;
    float dots[8];
    #pragma unroll
    for (int g=0; g<8; ++g) dots[g]=0.f;
    for (int c = lane; c < INNER_; c += 64) {
        float qv = qr[c], kv = kr[c], vv = vr[c];
        #pragma unroll
        for (int g=0; g<4; ++g) {
            dots[g]   += qv*Wig[g*768+c] + kv*Wig[g*768+256+c] + vv*Wig[g*768+512+c];
            dots[4+g] += qv*Wfg[g*768+c] + kv*Wfg[g*768+256+c] + vv*Wfg[g*768+512+c];
        }
    }
    #pragma unroll
    for (int off=32; off>0; off>>=1)
        #pragma unroll
        for (int g=0; g<8; ++g) dots[g] += __shfl_down(dots[g], off, 64);
    if (lane == 0) {
        #pragma unroll
        for (int g=0; g<4; ++g) {
            igp[((size_t)b*NH_+g)*S_ + s] = dots[g]   + big[g];
            fgp[((size_t)b*NH_+g)*S_ + s] = dots[4+g] + bfg[g];
        }
    }
}

// ---------------- mLSTM decay precompute: lc, a = ig - lc, prefix-max(a) ----------------
__global__ void mlstm_scan_pre(const float* __restrict__ igp, const float* __restrict__ fgp,
                               float* __restrict__ lc, float* __restrict__ av,
                               float* __restrict__ mx) {
    int bh = blockIdx.x; int t = threadIdx.x;  // 1024 threads
    __shared__ float buf[2][1024];
    float ls = logsig(fgp[(size_t)bh*S_ + t]);
    int cur = 0;
    buf[0][t] = ls; __syncthreads();
    for (int off=1; off<1024; off<<=1) {
        float x2 = buf[cur][t];
        if (t >= off) x2 += buf[cur][t-off];
        buf[cur^1][t] = x2; cur ^= 1; __syncthreads();
    }
    float lcv = buf[cur][t];
    lc[(size_t)bh*S_+t] = lcv;
    float a = igp[(size_t)bh*S_+t] - lcv;
    av[(size_t)bh*S_+t] = a;
    __syncthreads();
    cur = 0; buf[0][t] = a; __syncthreads();
    for (int off=1; off<1024; off<<=1) {
        float x2 = buf[cur][t];
        if (t >= off) x2 = fmaxf(x2, buf[cur][t-off]);
        buf[cur^1][t] = x2; cur ^= 1; __syncthreads();
    }
    mx[(size_t)bh*S_+t] = buf[cur][t];
}

// ---------------- mLSTM attention: tiled flash-style, 64 q-rows per block ----------------
// 256 threads = 4 waves in 2x2 over the 64x64 score tile; 4x4 register micro-tiles
// with j strided by 8 so LDS b128 reads are bank-conflict-free at stride 68.
__global__ __launch_bounds__(256) void mlstm_attn_tiled(
        const float* __restrict__ q, const float* __restrict__ k,
        const float* __restrict__ v, const float* __restrict__ lc,
        const float* __restrict__ av, const float* __restrict__ mx,
        float* __restrict__ hc) {
    int bid = blockIdx.x;
    int stile = 15 - (bid & 15);        // big tiles dispatch first (load balance)
    int bh = bid >> 4;
    int hh = bh & 3, b = bh >> 2;
    int s0 = stile << 6;
    int tid = threadIdx.x;
    int wid = tid >> 6, lane = tid & 63;
    int wy = wid >> 1, wx = wid & 1;
    int sg = lane >> 3, tg = lane & 7;

    __shared__ float qs[64*68];
    __shared__ float kst[64*68];   // K tile, then overwritten with P tile
    __shared__ float vtT[64*68];   // V tile transposed: vtT[d][t]
    __shared__ float avt[64], maxsL[64], normL[64], rsumL[128];

    const size_t bhS = (size_t)bh * S_;
    // ---- stage Q (scaled by 1/sqrt(64)=0.125) + per-row maxs ----
    {
        int r = tid >> 2, c0 = (tid & 3) << 4;
        const float* qg = q + ((size_t)(b*S_) + s0 + r)*INNER_ + hh*64;
        #pragma unroll
        for (int i = 0; i < 4; ++i) {
            float4 t4 = *(const float4*)(qg + c0 + 4*i);
            float4 w4; w4.x=t4.x*0.125f; w4.y=t4.y*0.125f; w4.z=t4.z*0.125f; w4.w=t4.w*0.125f;
            *(float4*)(&qs[r*68 + c0 + 4*i]) = w4;
        }
        if (tid < 64) maxsL[tid] = lc[bhS + s0 + tid] + mx[bhS + s0 + tid];
    }
    float msv[4];
    #pragma unroll
    for (int i = 0; i < 4; ++i)
        msv[i] = mx[bhS + s0 + 32*wy + 8*i + sg];

    float O[4][4];
    float rsAcc[4];
    #pragma unroll
    for (int i = 0; i < 4; ++i) {
        rsAcc[i] = 0.f;
        #pragma unroll
        for (int j = 0; j < 4; ++j) O[i][j] = 0.f;
    }

    for (int t0 = 0; t0 <= s0; t0 += 64) {
        __syncthreads();   // prev PV done (and Q staging on first iter)
        // ---- stage K tile (row-major) and V tile (transposed) ----
        {
            int r = tid >> 2, c0 = (tid & 3) << 4;
            const float* kg = k + ((size_t)(b*S_) + t0 + r)*INNER_ + hh*64;
            const float* vg = v + ((size_t)(b*S_) + t0 + r)*INNER_ + hh*64;
            #pragma unroll
            for (int i = 0; i < 4; ++i) {
                *(float4*)(&kst[r*68 + c0 + 4*i]) = *(const float4*)(kg + c0 + 4*i);
                float4 v4 = *(const float4*)(vg + c0 + 4*i);
                int dc = c0 + 4*i;
                vtT[(dc+0)*68 + r] = v4.x;
                vtT[(dc+1)*68 + r] = v4.y;
                vtT[(dc+2)*68 + r] = v4.z;
                vtT[(dc+3)*68 + r] = v4.w;
            }
            if (tid < 64) avt[tid] = av[bhS + t0 + tid];
        }
        __syncthreads();
        // ---- QK^T: dot[i][j] for s=32wy+8i+sg, t=32wx+8j+tg ----
        float dot[4][4];
        #pragma unroll
        for (int i = 0; i < 4; ++i)
            #pragma unroll
            for (int j = 0; j < 4; ++j) dot[i][j] = 0.f;
        {
            const float* qrow = &qs[(32*wy + sg)*68];
            const float* krow = &kst[(32*wx + tg)*68];
            for (int d = 0; d < 64; d += 4) {
                float4 a0 = *(const float4*)(qrow + 0*544 + d);
                float4 a1 = *(const float4*)(qrow + 1*544 + d);
                float4 a2 = *(const float4*)(qrow + 2*544 + d);
                float4 a3 = *(const float4*)(qrow + 3*544 + d);
                float4 b0 = *(const float4*)(krow + 0*544 + d);
                float4 b1 = *(const float4*)(krow + 1*544 + d);
                float4 b2 = *(const float4*)(krow + 2*544 + d);
                float4 b3 = *(const float4*)(krow + 3*544 + d);
                float4 A[4] = {a0,a1,a2,a3}, Bv[4] = {b0,b1,b2,b3};
                #pragma unroll
                for (int i = 0; i < 4; ++i)
                    #pragma unroll
                    for (int j = 0; j < 4; ++j)
                        dot[i][j] += A[i].x*Bv[j].x + A[i].y*Bv[j].y
                                   + A[i].z*Bv[j].z + A[i].w*Bv[j].w;
            }
        }
        __syncthreads();   // everyone done reading kst
        // ---- decay/mask, write P into kst's space, accumulate row sums ----
        #pragma unroll
        for (int i = 0; i < 4; ++i) {
            int s_loc = 32*wy + 8*i + sg;
            float rp = 0.f;
            #pragma unroll
            for (int j = 0; j < 4; ++j) {
                int t_loc = 32*wx + 8*j + tg;
                bool ok = (t0 + t_loc) <= (s0 + s_loc);
                float p = ok ? dot[i][j]*expf(avt[t_loc] - msv[i]) : 0.f;
                kst[s_loc*68 + t_loc] = p;
                rp += p;
            }
            rp += __shfl_xor(rp, 1);
            rp += __shfl_xor(rp, 2);
            rp += __shfl_xor(rp, 4);
            rsAcc[i] += rp;
        }
        __syncthreads();   // P fully written
        // ---- P @ V: O[i][j] for s=32wy+8i+sg, d=32wx+8j+tg ----
        {
            const float* prow = &kst[(32*wy + sg)*68];
            const float* vrow = &vtT[(32*wx + tg)*68];
            for (int tt = 0; tt < 64; tt += 4) {
                float4 a0 = *(const float4*)(prow + 0*544 + tt);
                float4 a1 = *(const float4*)(prow + 1*544 + tt);
                float4 a2 = *(const float4*)(prow + 2*544 + tt);
                float4 a3 = *(const float4*)(prow + 3*544 + tt);
                float4 b0 = *(const float4*)(vrow + 0*544 + tt);
                float4 b1 = *(const float4*)(vrow + 1*544 + tt);
                float4 b2 = *(const float4*)(vrow + 2*544 + tt);
                float4 b3 = *(const float4*)(vrow + 3*544 + tt);
                float4 A[4] = {a0,a1,a2,a3}, Bv[4] = {b0,b1,b2,b3};
                #pragma unroll
                for (int i = 0; i < 4; ++i)
                    #pragma unroll
                    for (int j = 0; j < 4; ++j)
                        O[i][j] += A[i].x*Bv[j].x + A[i].y*Bv[j].y
                                 + A[i].z*Bv[j].z + A[i].w*Bv[j].w;
            }
        }
    }
    // ---- combine row sums across the two wx waves ----
    if (tg == 0) {
        #pragma unroll
        for (int i = 0; i < 4; ++i)
            rsumL[wx*64 + 32*wy + 8*i + sg] = rsAcc[i];
    }
    __syncthreads();
    if (tid < 64) {
        float tot = rsumL[tid] + rsumL[64 + tid];
        normL[tid] = fmaxf(fabsf(tot), expf(-maxsL[tid])) + 1e-6f;
    }
    __syncthreads();
    #pragma unroll
    for (int i = 0; i < 4; ++i) {
        int s_loc = 32*wy + 8*i + sg;
        float inv = 1.0f / normL[s_loc];
        #pragma unroll
        for (int j = 0; j < 4; ++j) {
            int d_loc = 32*wx + 8*j + tg;
            hc[((size_t)(b*S_) + s0 + s_loc)*INNER_ + hh*64 + d_loc] = O[i][j] * inv;
        }
    }
}

// ---------------- mLSTM output: multihead LN (GS=64) + skip + gate ----------------
__global__ void mlstm_out(const float* __restrict__ hc, const float* __restrict__ xc,
                          const float* __restrict__ up, const float* __restrict__ onw,
                          const float* __restrict__ skip, float* __restrict__ hs) {
    int row = blockIdx.x; int c = threadIdx.x;  // 256 threads
    float v = hc[(size_t)row*INNER_ + c];
    __shared__ float s1[256], s2[256];
    s1[c]=v; s2[c]=v*v; __syncthreads();
    int li = c & 63;
    for (int off=32; off>0; off>>=1){
        if (li < off){ s1[c]+=s1[c+off]; s2[c]+=s2[c+off]; }
        __syncthreads();
    }
    int base = c & ~63;
    float mu = s1[base]*(1.f/64.f);
    float var = s2[base]*(1.f/64.f) - mu*mu;
    float ht = (v-mu)*rsqrtf(var+1e-5f)*onw[c];
    float z = up[(size_t)row*512 + 256 + c];
    hs[(size_t)row*INNER_ + c] = (ht + skip[c]*xc[(size_t)row*INNER_+c]) * (z*sigm(z));
}

// ---------------- sLSTM sequential scan: one block per (b,h) ----------------
__global__ __launch_bounds__(128) void slstm_scan(
        const float* __restrict__ gx, const float* __restrict__ R,
        const float* __restrict__ bb, float* __restrict__ ys) {
    int blk = blockIdx.x; int hh = blk & 3; int b = blk >> 2;
    int j = threadIdx.x;  // 128 threads: j = g*32+e
    __shared__ float RL[32*128];
    __shared__ float yL[32];
    __shared__ float rawL[128];
    for (int d = 0; d < 32; ++d)
        RL[d*128 + j] = R[(size_t)(hh*32 + d)*128 + j];
    float bj = bb[hh*128 + j];
    if (j < 32) yL[j] = 0.f;
    float cst = 0.f, nst = 0.f, mst = 0.f;
    __syncthreads();
    float gcur = gx[((size_t)(b*S_ + 0)*NH_ + hh)*128 + j];
    for (int t = 0; t < S_; ++t) {
        float gnext = (t+1 < S_) ? gx[((size_t)(b*S_ + t+1)*NH_ + hh)*128 + j] : 0.f;
        float raw = gcur + bj;
        #pragma unroll 8
        for (int d = 0; d < 32; ++d) raw += yL[d]*RL[d*128 + j];
        rawL[j] = raw; __syncthreads();
        if (j < 32) {
            float iraw = rawL[j], fraw = rawL[32+j], zraw = rawL[64+j], oraw = rawL[96+j];
            float lfm = mst + logsig(fraw);
            float mnew = (t == 0) ? iraw : fmaxf(iraw, lfm);
            float og = sigm(oraw);
            float igv = expf(iraw - mnew), fgv = expf(lfm - mnew);
            cst = fgv*cst + igv*tanhf(zraw);
            nst = fgv*nst + igv;
            mst = mnew;
            float y = og*cst/nst;
            yL[j] = y;
            ys[(size_t)(b*S_ + t)*128 + hh*32 + j] = y;
        }
        __syncthreads();
        gcur = gnext;
    }
}

// ---------------- sLSTM out: h += mh_ln(ys; GS=32) * gnw ----------------
__global__ void slstm_addnorm(const float* __restrict__ ys, const float* __restrict__ w,
                              float* __restrict__ h) {
    int row = blockIdx.x; int c = threadIdx.x;  // 128
    float v = ys[(size_t)row*128 + c];
    __shared__ float s1[128], s2[128];
    s1[c]=v; s2[c]=v*v; __syncthreads();
    int li = c & 31;
    for (int off=16; off>0; off>>=1){
        if (li < off){ s1[c]+=s1[c+off]; s2[c]+=s2[c+off]; }
        __syncthreads();
    }
    int base = c & ~31;
    float mu = s1[base]*(1.f/32.f);
    float var = s2[base]*(1.f/32.f) - mu*mu;
    h[(size_t)row*128 + c] += (v-mu)*rsqrtf(var+1e-5f)*w[c];
}

// ---------------- FFN activation: gelu(g) * u2 ----------------
__global__ void ffn_act(const float* __restrict__ u, float* __restrict__ act) {
    int idx = blockIdx.x*blockDim.x + threadIdx.x;
    int total = MROWS_*192;
    if (idx >= total) return;
    int j = idx % 192; int m = idx / 192;
    float g  = u[(size_t)m*384 + j];
    float u2 = u[(size_t)m*384 + 192 + j];
    float ge = 0.5f*g*(1.0f + erff(g*0.70710678118f));
    act[(size_t)m*192 + j] = ge*u2;
}

// ---------------- Final FC on last token ----------------
__global__ void final_fc(const float* __restrict__ hp, const float* __restrict__ fcW,
                         const float* __restrict__ fcb, float* __restrict__ out) {
    int b = blockIdx.x; int lane = threadIdx.x;  // 64
    const float* r = hp + ((size_t)b*S_ + (S_-1))*128;
    float acc = r[lane]*fcW[lane] + r[lane+64]*fcW[lane+64];
    #pragma unroll
    for (int off=32; off>0; off>>=1) acc += __shfl_down(acc, off, 64);
    if (lane == 0) out[b] = acc + fcb[0];
}

extern "C" void kernel_launch(void* const* d_in, const int* in_sizes, int n_in,
                              void* d_out, int out_size, void* d_ws, size_t ws_size,
                              hipStream_t stream) {
    const float* x       = (const float*)d_in[0];
    const float* W_in    = (const float*)d_in[1];
    const float* b_in    = (const float*)d_in[2];
    const float* ln0_w   = (const float*)d_in[3];
    const float* m_Wup   = (const float*)d_in[4];
    const float* m_bup   = (const float*)d_in[5];
    const float* m_convk = (const float*)d_in[6];
    const float* m_convb = (const float*)d_in[7];
    const float* m_Wq    = (const float*)d_in[8];
    const float* m_bq    = (const float*)d_in[9];
    const float* m_Wk    = (const float*)d_in[10];
    const float* m_bk    = (const float*)d_in[11];
    const float* m_Wv    = (const float*)d_in[12];
    const float* m_bv    = (const float*)d_in[13];
    const float* m_Wig   = (const float*)d_in[14];
    const float* m_big   = (const float*)d_in[15];
    const float* m_Wfg   = (const float*)d_in[16];
    const float* m_bfg   = (const float*)d_in[17];
    const float* m_onw   = (const float*)d_in[18];
    const float* m_skip  = (const float*)d_in[19];
    const float* m_Wd    = (const float*)d_in[20];
    const float* m_bd    = (const float*)d_in[21];
    const float* ln1_w   = (const float*)d_in[22];
    const float* s_convk = (const float*)d_in[23];
    const float* s_convb = (const float*)d_in[24];
    const float* s_Wi    = (const float*)d_in[25];
    const float* s_Wf    = (const float*)d_in[26];
    const float* s_Wz    = (const float*)d_in[27];
    const float* s_Wo    = (const float*)d_in[28];
    const float* s_R     = (const float*)d_in[29];
    const float* s_b     = (const float*)d_in[30];
    const float* s_gnw   = (const float*)d_in[31];
    const float* ffn_nw  = (const float*)d_in[32];
    const float* f_Wu    = (const float*)d_in[33];
    const float* f_bu    = (const float*)d_in[34];
    const float* f_Wd    = (const float*)d_in[35];
    const float* f_bd    = (const float*)d_in[36];
    const float* post_w  = (const float*)d_in[37];
    const float* fc_W    = (const float*)d_in[38];
    const float* fc_b    = (const float*)d_in[39];
    float* out = (float*)d_out;

    float* W = (float*)d_ws;
    const size_t M1 = 1048576;        // 8192*128
    float* h    = W;                   // 1M
    float* r    = W + 1*M1;            // 1M  (all LN outputs, incl. hp)
    float* up   = W + 2*M1;            // 4M  (xm = cols 0..255, z = cols 256..511); later u (3M)
    float* xc   = W + 6*M1;            // 2M  ; later rc (1M)
    float* q    = W + 8*M1;            // 2M  ; later hs, later act
    float* kbuf = W + 10*M1;           // 2M  \ later gx (4M)
    float* vbuf = W + 12*M1;           // 2M  /
    float* hc   = W + 14*M1;           // 2M  ; later ys (1M)
    float* igp  = W + 16*M1;           // 32K each
    float* fgp  = igp + 32768;
    float* lc   = fgp + 32768;
    float* av   = lc  + 32768;
    float* mx   = av  + 32768;
    float* hs   = q;
    float* gx   = kbuf;
    float* ys   = hc;
    float* rc   = xc;
    float* u    = up;
    float* act  = q;
    float* hp   = r;

    dim3 blk16(16,16);

    // 1. h = x @ W_in^T + b_in
    gemm_bias<<<dim3(128/32, MROWS_/32), blk16, 0, stream>>>(x, W_in, b_in, nullptr, h, MROWS_, 128, F_);
    // 2. r = LN(h)*ln0_w
    ln_kernel<<<MROWS_, 128, 0, stream>>>(h, ln0_w, r);
    // 3. up = r @ m_Wup^T + m_bup
    gemm_bias<<<dim3(512/32, MROWS_/32), blk16, 0, stream>>>(r, m_Wup, m_bup, nullptr, up, MROWS_, 512, 128);
    // 4. xc = silu(causal_conv(xm))
    conv_silu<<<(MROWS_*256)/256, 256, 0, stream>>>(up, 512, m_convk, m_convb, xc, 256, 256);
    // 5. q,k,v headwise
    headwise4<<<(MROWS_*256)/256, 256, 0, stream>>>(xc, 256, m_Wq, m_bq, q);
    headwise4<<<(MROWS_*256)/256, 256, 0, stream>>>(xc, 256, m_Wk, m_bk, kbuf);
    headwise4<<<(MROWS_*256)/256, 256, 0, stream>>>(up, 512, m_Wv, m_bv, vbuf);
    // 6. ig/fg projections
    gateproj<<<MROWS_, 64, 0, stream>>>(q, kbuf, vbuf, m_Wig, m_big, m_Wfg, m_bfg, igp, fgp);
    // 7. decay precompute
    mlstm_scan_pre<<<B_*NH_, 1024, 0, stream>>>(igp, fgp, lc, av, mx);
    // 8. attention (tiled)
    mlstm_attn_tiled<<<B_*NH_*16, 256, 0, stream>>>(q, kbuf, vbuf, lc, av, mx, hc);
    // 9. multihead LN + skip + gate
    mlstm_out<<<MROWS_, 256, 0, stream>>>(hc, xc, up, m_onw, m_skip, hs);
    // 10. h += hs @ m_Wd^T + m_bd
    gemm_bias<<<dim3(128/32, MROWS_/32), blk16, 0, stream>>>(hs, m_Wd, m_bd, h, h, MROWS_, 128, 256);
    // 11. r = LN(h)*ln1_w
    ln_kernel<<<MROWS_, 128, 0, stream>>>(h, ln1_w, r);
    // 12. rc = silu(causal_conv(r))
    conv_silu<<<(MROWS_*128)/256, 256, 0, stream>>>(r, 128, s_convk, s_convb, rc, 128, 128);
    // 13. sLSTM gates
    headwise_gate<<<(MROWS_*128)/256, 256, 0, stream>>>(rc, s_Wi, gx, 0);
    headwise_gate<<<(MROWS_*128)/256, 256, 0, stream>>>(rc, s_Wf, gx, 1);
    headwise_gate<<<(MROWS_*128)/256, 256, 0, stream>>>(r,  s_Wz, gx, 2);
    headwise_gate<<<(MROWS_*128)/256, 256, 0, stream>>>(r,  s_Wo, gx, 3);
    // 14. sequential scan
    slstm_scan<<<B_*NH_, 128, 0, stream>>>(gx, s_R, s_b, ys);
    // 15. h += mh_ln(ys)*s_gnw
    slstm_addnorm<<<MROWS_, 128, 0, stream>>>(ys, s_gnw, h);
    // 16. r = LN(h)*ffn_nw
    ln_kernel<<<MROWS_, 128, 0, stream>>>(h, ffn_nw, r);
    // 17. u = r @ f_Wu^T + f_bu
    gemm_bias<<<dim3(384/32, MROWS_/32), blk16, 0, stream>>>(r, f_Wu, f_bu, nullptr, u, MROWS_, 384, 128);
    // 18. act = gelu(g)*u2
    ffn_act<<<(MROWS_*192)/256, 256, 0, stream>>>(u, act);
    // 19. h += act @ f_Wd^T + f_bd
    gemm_bias<<<dim3(128/32, MROWS_/32), blk16, 0, stream>>>(act, f_Wd, f_bd, h, h, MROWS_, 128, 192);
    // 20. hp = LN(h)*post_w
    ln_kernel<<<MROWS_, 128, 0, stream>>>(h, post_w, hp);
    // 21. out = hp[:, -1, :] @ fc_W^T + fc_b
    final_fc<<<B_, 64, 0, stream>>>(hp, fc_W, fc_b, out);
    (void)in_sizes; (void)n_in; (void)out_size; (void)ws_size;
}

// Round 4
// 2345.046 us; speedup vs baseline: 2.3425x; 1.1933x over previous
//
#include <hip/hip_runtime.h>
#include <hip/hip_bf16.h>
#include <math.h>

#define B_ 8
#define S_ 1024
#define F_ 75
#define D_ 128
#define INNER_ 256
#define NH_ 4
#define DH_ 64
#define MROWS_ (B_*S_)   // 8192

static __device__ __forceinline__ float sigm(float x){ return 1.0f/(1.0f+expf(-x)); }
static __device__ __forceinline__ float logsig(float x){
    return (x >= 0.f) ? -log1pf(expf(-x)) : (x - log1pf(expf(x)));
}

// ---------------- Tiled GEMM: C = A @ W^T + bias (+ res) ----------------
// 64x64 tile, 256 threads = 4 waves in 2x2; 4x4 register micro-tiles strided
// by 8 (same conflict-free stride-68 pattern as the attention kernel).
__global__ __launch_bounds__(256) void gemm_bias_big(
        const float* __restrict__ A, const float* __restrict__ W,
        const float* __restrict__ bias, const float* __restrict__ res,
        float* __restrict__ C, int M, int N, int K) {
    __shared__ float As[64*68];
    __shared__ float Ws[64*68];
    int tid = threadIdx.x;
    int wid = tid >> 6, lane = tid & 63;
    int wy = wid >> 1, wx = wid & 1;
    int sg = lane >> 3, tg = lane & 7;
    int m0 = blockIdx.y*64, n0 = blockIdx.x*64;
    int r = tid >> 2, c0 = (tid & 3) << 4;
    bool vec = ((K & 3) == 0);
    float acc[4][4];
    #pragma unroll
    for (int i = 0; i < 4; ++i)
        #pragma unroll
        for (int j = 0; j < 4; ++j) acc[i][j] = 0.f;

    for (int k0 = 0; k0 < K; k0 += 64) {
        __syncthreads();
        const float* Ar = A + (size_t)(m0+r)*K + k0;
        const float* Wr = W + (size_t)(n0+r)*K + k0;
        if (vec) {   // K % 64 == 0 for all vec-eligible shapes here
            #pragma unroll
            for (int i = 0; i < 4; ++i) {
                *(float4*)(&As[r*68 + c0 + 4*i]) = *(const float4*)(Ar + c0 + 4*i);
                *(float4*)(&Ws[r*68 + c0 + 4*i]) = *(const float4*)(Wr + c0 + 4*i);
            }
        } else {
            #pragma unroll
            for (int i = 0; i < 4; ++i)
                #pragma unroll
                for (int e = 0; e < 4; ++e) {
                    int c = c0 + 4*i + e;
                    bool ok = (k0 + c) < K;
                    As[r*68 + c] = ok ? Ar[c] : 0.f;
                    Ws[r*68 + c] = ok ? Wr[c] : 0.f;
                }
        }
        __syncthreads();
        const float* arow = &As[(32*wy + sg)*68];
        const float* brow = &Ws[(32*wx + tg)*68];
        for (int d = 0; d < 64; d += 4) {
            float4 a0 = *(const float4*)(arow + 0*544 + d);
            float4 a1 = *(const float4*)(arow + 1*544 + d);
            float4 a2 = *(const float4*)(arow + 2*544 + d);
            float4 a3 = *(const float4*)(arow + 3*544 + d);
            float4 b0 = *(const float4*)(brow + 0*544 + d);
            float4 b1 = *(const float4*)(brow + 1*544 + d);
            float4 b2 = *(const float4*)(brow + 2*544 + d);
            float4 b3 = *(const float4*)(brow + 3*544 + d);
            float4 Av[4] = {a0,a1,a2,a3}, Bv[4] = {b0,b1,b2,b3};
            #pragma unroll
            for (int i = 0; i < 4; ++i)
                #pragma unroll
                for (int j = 0; j < 4; ++j)
                    acc[i][j] += Av[i].x*Bv[j].x + Av[i].y*Bv[j].y
                               + Av[i].z*Bv[j].z + Av[i].w*Bv[j].w;
        }
    }
    #pragma unroll
    for (int i = 0; i < 4; ++i) {
        int m = m0 + 32*wy + 8*i + sg;
        #pragma unroll
        for (int j = 0; j < 4; ++j) {
            int n = n0 + 32*wx + 8*j + tg;
            float v = acc[i][j] + bias[n];
            if (res) v += res[(size_t)m*N + n];
            C[(size_t)m*N + n] = v;
        }
    }
}

// ---------------- Plain LayerNorm over D=128 ----------------
__global__ void ln_kernel(const float* __restrict__ X, const float* __restrict__ w,
                          float* __restrict__ Y) {
    int row = blockIdx.x, t = threadIdx.x;  // 128 threads
    float v = X[(size_t)row*128 + t];
    __shared__ float s1[128], s2[128];
    s1[t]=v; s2[t]=v*v; __syncthreads();
    for (int off=64; off>0; off>>=1){
        if (t<off){ s1[t]+=s1[t+off]; s2[t]+=s2[t+off]; }
        __syncthreads();
    }
    float mu = s1[0]*(1.f/128.f);
    float var = s2[0]*(1.f/128.f) - mu*mu;
    Y[(size_t)row*128 + t] = (v-mu)*rsqrtf(var+1e-5f)*w[t];
}

// ---------------- Causal depthwise conv (K=4) + SiLU ----------------
__global__ void conv_silu(const float* __restrict__ X, int ldx,
                          const float* __restrict__ kw, const float* __restrict__ kb,
                          float* __restrict__ Y, int ldy, int C) {
    int idx = blockIdx.x*blockDim.x + threadIdx.x;
    int total = MROWS_*C;
    if (idx >= total) return;
    int c = idx % C; int bs = idx / C;
    int s = bs % S_; int b = bs / S_;
    float acc = kb[c];
    #pragma unroll
    for (int i = 0; i < 4; ++i) {
        int sp = s - 3 + i;
        if (sp >= 0) acc += X[((size_t)b*S_+sp)*ldx + c] * kw[c*4+i];
    }
    Y[((size_t)b*S_+s)*ldy + c] = acc * sigm(acc);
}

// ---------------- Headwise block-diagonal proj (mLSTM q/k/v, HS=4) ----------------
__global__ void headwise4(const float* __restrict__ X, int ldx,
                          const float* __restrict__ W, const float* __restrict__ bias,
                          float* __restrict__ Y) {
    int idx = blockIdx.x*blockDim.x + threadIdx.x;
    int total = MROWS_*INNER_;
    if (idx >= total) return;
    int co = idx % INNER_; int bs = idx / INNER_;
    int h = co >> 2, o = co & 3;
    const float* Wh = W + ((size_t)h*4 + o)*4;
    const float* xr = X + (size_t)bs*ldx + h*4;
    float acc = bias[co];
    #pragma unroll
    for (int i = 0; i < 4; ++i) acc += xr[i]*Wh[i];
    Y[(size_t)bs*INNER_ + co] = acc;
}

// ---------------- sLSTM headwise (HS=32) writing into gx slot g ----------------
__global__ void headwise_gate(const float* __restrict__ X, const float* __restrict__ W,
                              float* __restrict__ GX, int g) {
    int idx = blockIdx.x*blockDim.x + threadIdx.x;
    int total = MROWS_*128;
    if (idx >= total) return;
    int co = idx % 128; int bs = idx / 128;
    int h = co >> 5, o = co & 31;
    const float* Wh = W + ((size_t)h*32 + o)*32;
    const float* xr = X + (size_t)bs*128 + h*32;
    float acc = 0.f;
    #pragma unroll
    for (int i = 0; i < 32; ++i) acc += xr[i]*Wh[i];
    GX[(size_t)bs*512 + h*128 + g*32 + o] = acc;
}

// ---------------- ig/fg gate projection over concat(q,k,v) ----------------
__global__ void gateproj(const float* __restrict__ q, const float* __restrict__ k,
                         const float* __restrict__ v,
                         const float* __restrict__ Wig, const float* __restrict__ big,
                         const float* __restrict__ Wfg, const float* __restrict__ bfg,
                         float* __restrict__ igp, float* __restrict__ fgp) {
    int bs = blockIdx.x; int lane = threadIdx.x;  // 64 threads
    int b = bs / S_, s = bs % S_;
    const float* qr = q + (size_t)bs*INNER_;
    const float* kr = k + (size_t)bs*INNER_;
    const float* vr = v + (size_t)bs*INNER_;
    float dots[8];
    #pragma unroll
    for (int g=0; g<8; ++g) dots[g]=0.f;
    for (int c = lane; c < INNER_; c += 64) {
        float qv = qr[c], kv = kr[c], vv = vr[c];
        #pragma unroll
        for (int g=0; g<4; ++g) {
            dots[g]   += qv*Wig[g*768+c] + kv*Wig[g*768+256+c] + vv*Wig[g*768+512+c];
            dots[4+g] += qv*Wfg[g*768+c] + kv*Wfg[g*768+256+c] + vv*Wfg[g*768+512+c];
        }
    }
    #pragma unroll
    for (int off=32; off>0; off>>=1)
        #pragma unroll
        for (int g=0; g<8; ++g) dots[g] += __shfl_down(dots[g], off, 64);
    if (lane == 0) {
        #pragma unroll
        for (int g=0; g<4; ++g) {
            igp[((size_t)b*NH_+g)*S_ + s] = dots[g]   + big[g];
            fgp[((size_t)b*NH_+g)*S_ + s] = dots[4+g] + bfg[g];
        }
    }
}

// ---------------- mLSTM decay precompute: lc, a = ig - lc, prefix-max(a) ----------------
__global__ void mlstm_scan_pre(const float* __restrict__ igp, const float* __restrict__ fgp,
                               float* __restrict__ lc, float* __restrict__ av,
                               float* __restrict__ mx) {
    int bh = blockIdx.x; int t = threadIdx.x;  // 1024 threads
    __shared__ float buf[2][1024];
    float ls = logsig(fgp[(size_t)bh*S_ + t]);
    int cur = 0;
    buf[0][t] = ls; __syncthreads();
    for (int off=1; off<1024; off<<=1) {
        float x2 = buf[cur][t];
        if (t >= off) x2 += buf[cur][t-off];
        buf[cur^1][t] = x2; cur ^= 1; __syncthreads();
    }
    float lcv = buf[cur][t];
    lc[(size_t)bh*S_+t] = lcv;
    float a = igp[(size_t)bh*S_+t] - lcv;
    av[(size_t)bh*S_+t] = a;
    __syncthreads();
    cur = 0; buf[0][t] = a; __syncthreads();
    for (int off=1; off<1024; off<<=1) {
        float x2 = buf[cur][t];
        if (t >= off) x2 = fmaxf(x2, buf[cur][t-off]);
        buf[cur^1][t] = x2; cur ^= 1; __syncthreads();
    }
    mx[(size_t)bh*S_+t] = buf[cur][t];
}

// ---------------- mLSTM attention: tiled flash-style, 64 q-rows per block ----------------
__global__ __launch_bounds__(256) void mlstm_attn_tiled(
        const float* __restrict__ q, const float* __restrict__ k,
        const float* __restrict__ v, const float* __restrict__ lc,
        const float* __restrict__ av, const float* __restrict__ mx,
        float* __restrict__ hc) {
    int bid = blockIdx.x;
    int stile = 15 - (bid & 15);        // big tiles dispatch first (load balance)
    int bh = bid >> 4;
    int hh = bh & 3, b = bh >> 2;
    int s0 = stile << 6;
    int tid = threadIdx.x;
    int wid = tid >> 6, lane = tid & 63;
    int wy = wid >> 1, wx = wid & 1;
    int sg = lane >> 3, tg = lane & 7;

    __shared__ float qs[64*68];
    __shared__ float kst[64*68];   // K tile, then overwritten with P tile
    __shared__ float vtT[64*68];   // V tile transposed: vtT[d][t]
    __shared__ float avt[64], maxsL[64], normL[64], rsumL[128];

    const size_t bhS = (size_t)bh * S_;
    {
        int r = tid >> 2, c0 = (tid & 3) << 4;
        const float* qg = q + ((size_t)(b*S_) + s0 + r)*INNER_ + hh*64;
        #pragma unroll
        for (int i = 0; i < 4; ++i) {
            float4 t4 = *(const float4*)(qg + c0 + 4*i);
            float4 w4; w4.x=t4.x*0.125f; w4.y=t4.y*0.125f; w4.z=t4.z*0.125f; w4.w=t4.w*0.125f;
            *(float4*)(&qs[r*68 + c0 + 4*i]) = w4;
        }
        if (tid < 64) maxsL[tid] = lc[bhS + s0 + tid] + mx[bhS + s0 + tid];
    }
    float msv[4];
    #pragma unroll
    for (int i = 0; i < 4; ++i)
        msv[i] = mx[bhS + s0 + 32*wy + 8*i + sg];

    float O[4][4];
    float rsAcc[4];
    #pragma unroll
    for (int i = 0; i < 4; ++i) {
        rsAcc[i] = 0.f;
        #pragma unroll
        for (int j = 0; j < 4; ++j) O[i][j] = 0.f;
    }

    for (int t0 = 0; t0 <= s0; t0 += 64) {
        __syncthreads();
        {
            int r = tid >> 2, c0 = (tid & 3) << 4;
            const float* kg = k + ((size_t)(b*S_) + t0 + r)*INNER_ + hh*64;
            const float* vg = v + ((size_t)(b*S_) + t0 + r)*INNER_ + hh*64;
            #pragma unroll
            for (int i = 0; i < 4; ++i) {
                *(float4*)(&kst[r*68 + c0 + 4*i]) = *(const float4*)(kg + c0 + 4*i);
                float4 v4 = *(const float4*)(vg + c0 + 4*i);
                int dc = c0 + 4*i;
                vtT[(dc+0)*68 + r] = v4.x;
                vtT[(dc+1)*68 + r] = v4.y;
                vtT[(dc+2)*68 + r] = v4.z;
                vtT[(dc+3)*68 + r] = v4.w;
            }
            if (tid < 64) avt[tid] = av[bhS + t0 + tid];
        }
        __syncthreads();
        float dot[4][4];
        #pragma unroll
        for (int i = 0; i < 4; ++i)
            #pragma unroll
            for (int j = 0; j < 4; ++j) dot[i][j] = 0.f;
        {
            const float* qrow = &qs[(32*wy + sg)*68];
            const float* krow = &kst[(32*wx + tg)*68];
            for (int d = 0; d < 64; d += 4) {
                float4 a0 = *(const float4*)(qrow + 0*544 + d);
                float4 a1 = *(const float4*)(qrow + 1*544 + d);
                float4 a2 = *(const float4*)(qrow + 2*544 + d);
                float4 a3 = *(const float4*)(qrow + 3*544 + d);
                float4 b0 = *(const float4*)(krow + 0*544 + d);
                float4 b1 = *(const float4*)(krow + 1*544 + d);
                float4 b2 = *(const float4*)(krow + 2*544 + d);
                float4 b3 = *(const float4*)(krow + 3*544 + d);
                float4 A[4] = {a0,a1,a2,a3}, Bv[4] = {b0,b1,b2,b3};
                #pragma unroll
                for (int i = 0; i < 4; ++i)
                    #pragma unroll
                    for (int j = 0; j < 4; ++j)
                        dot[i][j] += A[i].x*Bv[j].x + A[i].y*Bv[j].y
                                   + A[i].z*Bv[j].z + A[i].w*Bv[j].w;
            }
        }
        __syncthreads();
        #pragma unroll
        for (int i = 0; i < 4; ++i) {
            int s_loc = 32*wy + 8*i + sg;
            float rp = 0.f;
            #pragma unroll
            for (int j = 0; j < 4; ++j) {
                int t_loc = 32*wx + 8*j + tg;
                bool ok = (t0 + t_loc) <= (s0 + s_loc);
                float p = ok ? dot[i][j]*expf(avt[t_loc] - msv[i]) : 0.f;
                kst[s_loc*68 + t_loc] = p;
                rp += p;
            }
            rp += __shfl_xor(rp, 1);
            rp += __shfl_xor(rp, 2);
            rp += __shfl_xor(rp, 4);
            rsAcc[i] += rp;
        }
        __syncthreads();
        {
            const float* prow = &kst[(32*wy + sg)*68];
            const float* vrow = &vtT[(32*wx + tg)*68];
            for (int tt = 0; tt < 64; tt += 4) {
                float4 a0 = *(const float4*)(prow + 0*544 + tt);
                float4 a1 = *(const float4*)(prow + 1*544 + tt);
                float4 a2 = *(const float4*)(prow + 2*544 + tt);
                float4 a3 = *(const float4*)(prow + 3*544 + tt);
                float4 b0 = *(const float4*)(vrow + 0*544 + tt);
                float4 b1 = *(const float4*)(vrow + 1*544 + tt);
                float4 b2 = *(const float4*)(vrow + 2*544 + tt);
                float4 b3 = *(const float4*)(vrow + 3*544 + tt);
                float4 A[4] = {a0,a1,a2,a3}, Bv[4] = {b0,b1,b2,b3};
                #pragma unroll
                for (int i = 0; i < 4; ++i)
                    #pragma unroll
                    for (int j = 0; j < 4; ++j)
                        O[i][j] += A[i].x*Bv[j].x + A[i].y*Bv[j].y
                                 + A[i].z*Bv[j].z + A[i].w*Bv[j].w;
            }
        }
    }
    if (tg == 0) {
        #pragma unroll
        for (int i = 0; i < 4; ++i)
            rsumL[wx*64 + 32*wy + 8*i + sg] = rsAcc[i];
    }
    __syncthreads();
    if (tid < 64) {
        float tot = rsumL[tid] + rsumL[64 + tid];
        normL[tid] = fmaxf(fabsf(tot), expf(-maxsL[tid])) + 1e-6f;
    }
    __syncthreads();
    #pragma unroll
    for (int i = 0; i < 4; ++i) {
        int s_loc = 32*wy + 8*i + sg;
        float inv = 1.0f / normL[s_loc];
        #pragma unroll
        for (int j = 0; j < 4; ++j) {
            int d_loc = 32*wx + 8*j + tg;
            hc[((size_t)(b*S_) + s0 + s_loc)*INNER_ + hh*64 + d_loc] = O[i][j] * inv;
        }
    }
}

// ---------------- mLSTM output: multihead LN (GS=64) + skip + gate ----------------
__global__ void mlstm_out(const float* __restrict__ hc, const float* __restrict__ xc,
                          const float* __restrict__ up, const float* __restrict__ onw,
                          const float* __restrict__ skip, float* __restrict__ hs) {
    int row = blockIdx.x; int c = threadIdx.x;  // 256 threads
    float v = hc[(size_t)row*INNER_ + c];
    __shared__ float s1[256], s2[256];
    s1[c]=v; s2[c]=v*v; __syncthreads();
    int li = c & 63;
    for (int off=32; off>0; off>>=1){
        if (li < off){ s1[c]+=s1[c+off]; s2[c]+=s2[c+off]; }
        __syncthreads();
    }
    int base = c & ~63;
    float mu = s1[base]*(1.f/64.f);
    float var = s2[base]*(1.f/64.f) - mu*mu;
    float ht = (v-mu)*rsqrtf(var+1e-5f)*onw[c];
    float z = up[(size_t)row*512 + 256 + c];
    hs[(size_t)row*INNER_ + c] = (ht + skip[c]*xc[(size_t)row*INNER_+c]) * (z*sigm(z));
}

// ---------------- sLSTM scan: ONE WAVE per (b,h), R in registers ----------------
// Lane l owns raw entries j0=l, j1=l+64. Lanes 0..31 own state for e=l.
// y broadcast via 32-float LDS buffer; gx prefetched 4 steps ahead.
__global__ __launch_bounds__(64) void slstm_scan_wave(
        const float* __restrict__ gx, const float* __restrict__ R,
        const float* __restrict__ bb, float* __restrict__ ys) {
    int blk = blockIdx.x; int hh = blk & 3; int b = blk >> 2;
    int l = threadIdx.x;  // 0..63
    float Rc0[32], Rc1[32];
    #pragma unroll
    for (int d = 0; d < 32; ++d) {
        Rc0[d] = R[(size_t)(hh*32 + d)*128 + l];
        Rc1[d] = R[(size_t)(hh*32 + d)*128 + l + 64];
    }
    float bj0 = bb[hh*128 + l], bj1 = bb[hh*128 + l + 64];
    __shared__ __align__(16) float yL[32];
    if (l < 32) yL[l] = 0.f;
    __syncthreads();
    float cst = 0.f, nst = 0.f, mst = 0.f;
    const float* gbase = gx + (size_t)(b*S_)*512 + hh*128;
    float* ybase = ys + (size_t)(b*S_)*128 + hh*32;
    float ga[4], gb[4];
    #pragma unroll
    for (int u = 0; u < 4; ++u) {
        ga[u] = gbase[(size_t)u*512 + l];
        gb[u] = gbase[(size_t)u*512 + l + 64];
    }
    for (int t = 0; t < S_; t += 4) {
        float gna[4], gnb[4];
        #pragma unroll
        for (int u = 0; u < 4; ++u) {
            int tn = t + 4 + u;
            size_t off = (size_t)(tn < S_ ? tn : 0) * 512;
            gna[u] = gbase[off + l];
            gnb[u] = gbase[off + l + 64];
        }
        #pragma unroll
        for (int u = 0; u < 4; ++u) {
            // pull y into registers (broadcast reads, conflict-free)
            float yv[32];
            #pragma unroll
            for (int i = 0; i < 8; ++i) {
                float4 t4 = ((const float4*)yL)[i];
                yv[4*i]=t4.x; yv[4*i+1]=t4.y; yv[4*i+2]=t4.z; yv[4*i+3]=t4.w;
            }
            float a00=0.f,a01=0.f,a02=0.f,a03=0.f;
            float a10=0.f,a11=0.f,a12=0.f,a13=0.f;
            #pragma unroll
            for (int d = 0; d < 32; d += 4) {
                a00 += yv[d+0]*Rc0[d+0];  a10 += yv[d+0]*Rc1[d+0];
                a01 += yv[d+1]*Rc0[d+1];  a11 += yv[d+1]*Rc1[d+1];
                a02 += yv[d+2]*Rc0[d+2];  a12 += yv[d+2]*Rc1[d+2];
                a03 += yv[d+3]*Rc0[d+3];  a13 += yv[d+3]*Rc1[d+3];
            }
            float r0 = ga[u] + bj0 + ((a00+a01)+(a02+a03));
            float r1 = gb[u] + bj1 + ((a10+a11)+(a12+a13));
            // lanes<32: r0=iraw[e], r1=zraw[e]; lanes>=32: r0=fraw[e], r1=oraw[e]
            float fo0 = __shfl_xor(r0, 32, 64);
            float fo1 = __shfl_xor(r1, 32, 64);
            int t_abs = t + u;
            if (l < 32) {
                float iraw = r0, zraw = r1, fraw = fo0, oraw = fo1;
                float lfm = mst + logsig(fraw);
                float mnew = (t_abs == 0) ? iraw : fmaxf(iraw, lfm);
                float og = sigm(oraw);
                float igv = expf(iraw - mnew), fgv = expf(lfm - mnew);
                cst = fgv*cst + igv*tanhf(zraw);
                nst = fgv*nst + igv;
                mst = mnew;
                float y = og*cst/nst;
                ybase[(size_t)t_abs*128 + l] = y;
                yL[l] = y;
            }
            __syncthreads();
        }
        #pragma unroll
        for (int u = 0; u < 4; ++u) { ga[u] = gna[u]; gb[u] = gnb[u]; }
    }
}

// ---------------- sLSTM out: h += mh_ln(ys; GS=32) * gnw ----------------
__global__ void slstm_addnorm(const float* __restrict__ ys, const float* __restrict__ w,
                              float* __restrict__ h) {
    int row = blockIdx.x; int c = threadIdx.x;  // 128
    float v = ys[(size_t)row*128 + c];
    __shared__ float s1[128], s2[128];
    s1[c]=v; s2[c]=v*v; __syncthreads();
    int li = c & 31;
    for (int off=16; off>0; off>>=1){
        if (li < off){ s1[c]+=s1[c+off]; s2[c]+=s2[c+off]; }
        __syncthreads();
    }
    int base = c & ~31;
    float mu = s1[base]*(1.f/32.f);
    float var = s2[base]*(1.f/32.f) - mu*mu;
    h[(size_t)row*128 + c] += (v-mu)*rsqrtf(var+1e-5f)*w[c];
}

// ---------------- FFN activation: gelu(g) * u2 ----------------
__global__ void ffn_act(const float* __restrict__ u, float* __restrict__ act) {
    int idx = blockIdx.x*blockDim.x + threadIdx.x;
    int total = MROWS_*192;
    if (idx >= total) return;
    int j = idx % 192; int m = idx / 192;
    float g  = u[(size_t)m*384 + j];
    float u2 = u[(size_t)m*384 + 192 + j];
    float ge = 0.5f*g*(1.0f + erff(g*0.70710678118f));
    act[(size_t)m*192 + j] = ge*u2;
}

// ---------------- Final FC on last token ----------------
__global__ void final_fc(const float* __restrict__ hp, const float* __restrict__ fcW,
                         const float* __restrict__ fcb, float* __restrict__ out) {
    int b = blockIdx.x; int lane = threadIdx.x;  // 64
    const float* r = hp + ((size_t)b*S_ + (S_-1))*128;
    float acc = r[lane]*fcW[lane] + r[lane+64]*fcW[lane+64];
    #pragma unroll
    for (int off=32; off>0; off>>=1) acc += __shfl_down(acc, off, 64);
    if (lane == 0) out[b] = acc + fcb[0];
}

extern "C" void kernel_launch(void* const* d_in, const int* in_sizes, int n_in,
                              void* d_out, int out_size, void* d_ws, size_t ws_size,
                              hipStream_t stream) {
    const float* x       = (const float*)d_in[0];
    const float* W_in    = (const float*)d_in[1];
    const float* b_in    = (const float*)d_in[2];
    const float* ln0_w   = (const float*)d_in[3];
    const float* m_Wup   = (const float*)d_in[4];
    const float* m_bup   = (const float*)d_in[5];
    const float* m_convk = (const float*)d_in[6];
    const float* m_convb = (const float*)d_in[7];
    const float* m_Wq    = (const float*)d_in[8];
    const float* m_bq    = (const float*)d_in[9];
    const float* m_Wk    = (const float*)d_in[10];
    const float* m_bk    = (const float*)d_in[11];
    const float* m_Wv    = (const float*)d_in[12];
    const float* m_bv    = (const float*)d_in[13];
    const float* m_Wig   = (const float*)d_in[14];
    const float* m_big   = (const float*)d_in[15];
    const float* m_Wfg   = (const float*)d_in[16];
    const float* m_bfg   = (const float*)d_in[17];
    const float* m_onw   = (const float*)d_in[18];
    const float* m_skip  = (const float*)d_in[19];
    const float* m_Wd    = (const float*)d_in[20];
    const float* m_bd    = (const float*)d_in[21];
    const float* ln1_w   = (const float*)d_in[22];
    const float* s_convk = (const float*)d_in[23];
    const float* s_convb = (const float*)d_in[24];
    const float* s_Wi    = (const float*)d_in[25];
    const float* s_Wf    = (const float*)d_in[26];
    const float* s_Wz    = (const float*)d_in[27];
    const float* s_Wo    = (const float*)d_in[28];
    const float* s_R     = (const float*)d_in[29];
    const float* s_b     = (const float*)d_in[30];
    const float* s_gnw   = (const float*)d_in[31];
    const float* ffn_nw  = (const float*)d_in[32];
    const float* f_Wu    = (const float*)d_in[33];
    const float* f_bu    = (const float*)d_in[34];
    const float* f_Wd    = (const float*)d_in[35];
    const float* f_bd    = (const float*)d_in[36];
    const float* post_w  = (const float*)d_in[37];
    const float* fc_W    = (const float*)d_in[38];
    const float* fc_b    = (const float*)d_in[39];
    float* out = (float*)d_out;

    float* W = (float*)d_ws;
    const size_t M1 = 1048576;        // 8192*128
    float* h    = W;                   // 1M
    float* r    = W + 1*M1;            // 1M
    float* up   = W + 2*M1;            // 4M
    float* xc   = W + 6*M1;            // 2M
    float* q    = W + 8*M1;            // 2M
    float* kbuf = W + 10*M1;           // 2M
    float* vbuf = W + 12*M1;           // 2M
    float* hc   = W + 14*M1;           // 2M
    float* igp  = W + 16*M1;
    float* fgp  = igp + 32768;
    float* lc   = fgp + 32768;
    float* av   = lc  + 32768;
    float* mx   = av  + 32768;
    float* hs   = q;
    float* gx   = kbuf;
    float* ys   = hc;
    float* rc   = xc;
    float* u    = up;
    float* act  = q;
    float* hp   = r;

    // 1. h = x @ W_in^T + b_in   (M=8192, N=128, K=75 → scalar staging path)
    gemm_bias_big<<<dim3(128/64, MROWS_/64), 256, 0, stream>>>(x, W_in, b_in, nullptr, h, MROWS_, 128, F_);
    // 2. r = LN(h)*ln0_w
    ln_kernel<<<MROWS_, 128, 0, stream>>>(h, ln0_w, r);
    // 3. up = r @ m_Wup^T + m_bup
    gemm_bias_big<<<dim3(512/64, MROWS_/64), 256, 0, stream>>>(r, m_Wup, m_bup, nullptr, up, MROWS_, 512, 128);
    // 4. xc = silu(causal_conv(xm))
    conv_silu<<<(MROWS_*256)/256, 256, 0, stream>>>(up, 512, m_convk, m_convb, xc, 256, 256);
    // 5. q,k,v headwise
    headwise4<<<(MROWS_*256)/256, 256, 0, stream>>>(xc, 256, m_Wq, m_bq, q);
    headwise4<<<(MROWS_*256)/256, 256, 0, stream>>>(xc, 256, m_Wk, m_bk, kbuf);
    headwise4<<<(MROWS_*256)/256, 256, 0, stream>>>(up, 512, m_Wv, m_bv, vbuf);
    // 6. ig/fg projections
    gateproj<<<MROWS_, 64, 0, stream>>>(q, kbuf, vbuf, m_Wig, m_big, m_Wfg, m_bfg, igp, fgp);
    // 7. decay precompute
    mlstm_scan_pre<<<B_*NH_, 1024, 0, stream>>>(igp, fgp, lc, av, mx);
    // 8. attention (tiled)
    mlstm_attn_tiled<<<B_*NH_*16, 256, 0, stream>>>(q, kbuf, vbuf, lc, av, mx, hc);
    // 9. multihead LN + skip + gate
    mlstm_out<<<MROWS_, 256, 0, stream>>>(hc, xc, up, m_onw, m_skip, hs);
    // 10. h += hs @ m_Wd^T + m_bd
    gemm_bias_big<<<dim3(128/64, MROWS_/64), 256, 0, stream>>>(hs, m_Wd, m_bd, h, h, MROWS_, 128, 256);
    // 11. r = LN(h)*ln1_w
    ln_kernel<<<MROWS_, 128, 0, stream>>>(h, ln1_w, r);
    // 12. rc = silu(causal_conv(r))
    conv_silu<<<(MROWS_*128)/256, 256, 0, stream>>>(r, 128, s_convk, s_convb, rc, 128, 128);
    // 13. sLSTM gates
    headwise_gate<<<(MROWS_*128)/256, 256, 0, stream>>>(rc, s_Wi, gx, 0);
    headwise_gate<<<(MROWS_*128)/256, 256, 0, stream>>>(rc, s_Wf, gx, 1);
    headwise_gate<<<(MROWS_*128)/256, 256, 0, stream>>>(r,  s_Wz, gx, 2);
    headwise_gate<<<(MROWS_*128)/256, 256, 0, stream>>>(r,  s_Wo, gx, 3);
    // 14. sequential scan (single wave per (b,h))
    slstm_scan_wave<<<B_*NH_, 64, 0, stream>>>(gx, s_R, s_b, ys);
    // 15. h += mh_ln(ys)*s_gnw
    slstm_addnorm<<<MROWS_, 128, 0, stream>>>(ys, s_gnw, h);
    // 16. r = LN(h)*ffn_nw
    ln_kernel<<<MROWS_, 128, 0, stream>>>(h, ffn_nw, r);
    // 17. u = r @ f_Wu^T + f_bu
    gemm_bias_big<<<dim3(384/64, MROWS_/64), 256, 0, stream>>>(r, f_Wu, f_bu, nullptr, u, MROWS_, 384, 128);
    // 18. act = gelu(g)*u2
    ffn_act<<<(MROWS_*192)/256, 256, 0, stream>>>(u, act);
    // 19. h += act @ f_Wd^T + f_bd
    gemm_bias_big<<<dim3(128/64, MROWS_/64), 256, 0, stream>>>(act, f_Wd, f_bd, h, h, MROWS_, 128, 192);
    // 20. hp = LN(h)*post_w
    ln_kernel<<<MROWS_, 128, 0, stream>>>(h, post_w, hp);
    // 21. out = hp[:, -1, :] @ fc_W^T + fc_b
    final_fc<<<B_, 64, 0, stream>>>(hp, fc_W, fc_b, out);
    (void)in_sizes; (void)n_in; (void)out_size; (void)ws_size;
}

// Round 5
// 1499.082 us; speedup vs baseline: 3.6644x; 1.5643x over previous
//
#include <hip/hip_runtime.h>
#include <hip/hip_bf16.h>
#include <math.h>

#define B_ 8
#define S_ 1024
#define F_ 75
#define D_ 128
#define INNER_ 256
#define NH_ 4
#define DH_ 64
#define MROWS_ (B_*S_)   // 8192

static __device__ __forceinline__ float frcp(float x){ return __builtin_amdgcn_rcpf(x); }
static __device__ __forceinline__ float fsigm(float x){ return frcp(1.0f + __expf(-x)); }
static __device__ __forceinline__ float flogsig(float x){
    return fminf(x, 0.f) - __logf(1.0f + __expf(-fabsf(x)));
}
static __device__ __forceinline__ float ftanh(float z){
    return 1.0f - 2.0f*frcp(__expf(2.0f*z) + 1.0f);
}
static __device__ __forceinline__ float sigm(float x){ return 1.0f/(1.0f+expf(-x)); }
static __device__ __forceinline__ float logsig(float x){
    return (x >= 0.f) ? -log1pf(expf(-x)) : (x - log1pf(expf(x)));
}

// ---------------- Tiled GEMM: C = A @ W^T + bias (+ res) ----------------
// 64x64 tile, 256 threads = 4 waves in 2x2; 4x4 register micro-tiles strided
// by 8 (conflict-free stride-68 pattern).
__global__ __launch_bounds__(256) void gemm_bias_big(
        const float* __restrict__ A, const float* __restrict__ W,
        const float* __restrict__ bias, const float* __restrict__ res,
        float* __restrict__ C, int M, int N, int K) {
    __shared__ float As[64*68];
    __shared__ float Ws[64*68];
    int tid = threadIdx.x;
    int wid = tid >> 6, lane = tid & 63;
    int wy = wid >> 1, wx = wid & 1;
    int sg = lane >> 3, tg = lane & 7;
    int m0 = blockIdx.y*64, n0 = blockIdx.x*64;
    int r = tid >> 2, c0 = (tid & 3) << 4;
    bool vec = ((K & 3) == 0);
    float acc[4][4];
    #pragma unroll
    for (int i = 0; i < 4; ++i)
        #pragma unroll
        for (int j = 0; j < 4; ++j) acc[i][j] = 0.f;

    for (int k0 = 0; k0 < K; k0 += 64) {
        __syncthreads();
        const float* Ar = A + (size_t)(m0+r)*K + k0;
        const float* Wr = W + (size_t)(n0+r)*K + k0;
        if (vec) {
            #pragma unroll
            for (int i = 0; i < 4; ++i) {
                *(float4*)(&As[r*68 + c0 + 4*i]) = *(const float4*)(Ar + c0 + 4*i);
                *(float4*)(&Ws[r*68 + c0 + 4*i]) = *(const float4*)(Wr + c0 + 4*i);
            }
        } else {
            #pragma unroll
            for (int i = 0; i < 4; ++i)
                #pragma unroll
                for (int e = 0; e < 4; ++e) {
                    int c = c0 + 4*i + e;
                    bool ok = (k0 + c) < K;
                    As[r*68 + c] = ok ? Ar[c] : 0.f;
                    Ws[r*68 + c] = ok ? Wr[c] : 0.f;
                }
        }
        __syncthreads();
        const float* arow = &As[(32*wy + sg)*68];
        const float* brow = &Ws[(32*wx + tg)*68];
        for (int d = 0; d < 64; d += 4) {
            float4 a0 = *(const float4*)(arow + 0*544 + d);
            float4 a1 = *(const float4*)(arow + 1*544 + d);
            float4 a2 = *(const float4*)(arow + 2*544 + d);
            float4 a3 = *(const float4*)(arow + 3*544 + d);
            float4 b0 = *(const float4*)(brow + 0*544 + d);
            float4 b1 = *(const float4*)(brow + 1*544 + d);
            float4 b2 = *(const float4*)(brow + 2*544 + d);
            float4 b3 = *(const float4*)(brow + 3*544 + d);
            float4 Av[4] = {a0,a1,a2,a3}, Bv[4] = {b0,b1,b2,b3};
            #pragma unroll
            for (int i = 0; i < 4; ++i)
                #pragma unroll
                for (int j = 0; j < 4; ++j)
                    acc[i][j] += Av[i].x*Bv[j].x + Av[i].y*Bv[j].y
                               + Av[i].z*Bv[j].z + Av[i].w*Bv[j].w;
        }
    }
    #pragma unroll
    for (int i = 0; i < 4; ++i) {
        int m = m0 + 32*wy + 8*i + sg;
        #pragma unroll
        for (int j = 0; j < 4; ++j) {
            int n = n0 + 32*wx + 8*j + tg;
            float v = acc[i][j] + bias[n];
            if (res) v += res[(size_t)m*N + n];
            C[(size_t)m*N + n] = v;
        }
    }
}

// ---------------- Plain LayerNorm over D=128 ----------------
__global__ void ln_kernel(const float* __restrict__ X, const float* __restrict__ w,
                          float* __restrict__ Y) {
    int row = blockIdx.x, t = threadIdx.x;  // 128 threads
    float v = X[(size_t)row*128 + t];
    __shared__ float s1[128], s2[128];
    s1[t]=v; s2[t]=v*v; __syncthreads();
    for (int off=64; off>0; off>>=1){
        if (t<off){ s1[t]+=s1[t+off]; s2[t]+=s2[t+off]; }
        __syncthreads();
    }
    float mu = s1[0]*(1.f/128.f);
    float var = s2[0]*(1.f/128.f) - mu*mu;
    Y[(size_t)row*128 + t] = (v-mu)*rsqrtf(var+1e-5f)*w[t];
}

// ---------------- Causal depthwise conv (K=4) + SiLU ----------------
__global__ void conv_silu(const float* __restrict__ X, int ldx,
                          const float* __restrict__ kw, const float* __restrict__ kb,
                          float* __restrict__ Y, int ldy, int C) {
    int idx = blockIdx.x*blockDim.x + threadIdx.x;
    int total = MROWS_*C;
    if (idx >= total) return;
    int c = idx % C; int bs = idx / C;
    int s = bs % S_; int b = bs / S_;
    float acc = kb[c];
    #pragma unroll
    for (int i = 0; i < 4; ++i) {
        int sp = s - 3 + i;
        if (sp >= 0) acc += X[((size_t)b*S_+sp)*ldx + c] * kw[c*4+i];
    }
    Y[((size_t)b*S_+s)*ldy + c] = acc * fsigm(acc);
}

// ---------------- Headwise block-diagonal proj (mLSTM q/k/v, HS=4) ----------------
__global__ void headwise4(const float* __restrict__ X, int ldx,
                          const float* __restrict__ W, const float* __restrict__ bias,
                          float* __restrict__ Y) {
    int idx = blockIdx.x*blockDim.x + threadIdx.x;
    int total = MROWS_*INNER_;
    if (idx >= total) return;
    int co = idx % INNER_; int bs = idx / INNER_;
    int h = co >> 2, o = co & 3;
    const float* Wh = W + ((size_t)h*4 + o)*4;
    const float* xr = X + (size_t)bs*ldx + h*4;
    float acc = bias[co];
    #pragma unroll
    for (int i = 0; i < 4; ++i) acc += xr[i]*Wh[i];
    Y[(size_t)bs*INNER_ + co] = acc;
}

// ---------------- sLSTM all-4-gates headwise (HS=32) ----------------
__global__ void slstm_gates(const float* __restrict__ rc, const float* __restrict__ r,
                            const float* __restrict__ Wi, const float* __restrict__ Wf,
                            const float* __restrict__ Wz, const float* __restrict__ Wo,
                            float* __restrict__ GX) {
    int idx = blockIdx.x*blockDim.x + threadIdx.x;
    int total = MROWS_*128;
    if (idx >= total) return;
    int co = idx % 128; int bs = idx / 128;
    int h = co >> 5, o = co & 31;
    size_t wb = ((size_t)h*32 + o)*32;
    const float* xc_ = rc + (size_t)bs*128 + h*32;
    const float* xr_ = r  + (size_t)bs*128 + h*32;
    float di=0.f, df=0.f, dz=0.f, dو=0.f;
    #pragma unroll
    for (int i = 0; i < 32; ++i) {
        float a = xc_[i], c = xr_[i];
        di += a*Wi[wb+i];
        df += a*Wf[wb+i];
        dz += c*Wz[wb+i];
        dو += c*Wo[wb+i];
    }
    float* g = GX + (size_t)bs*512 + h*128 + o;
    g[0]  = di;
    g[32] = df;
    g[64] = dz;
    g[96] = dو;
}

// ---------------- ig/fg gate projection over concat(q,k,v) ----------------
__global__ void gateproj(const float* __restrict__ q, const float* __restrict__ k,
                         const float* __restrict__ v,
                         const float* __restrict__ Wig, const float* __restrict__ big,
                         const float* __restrict__ Wfg, const float* __restrict__ bfg,
                         float* __restrict__ igp, float* __restrict__ fgp) {
    int bs = blockIdx.x; int lane = threadIdx.x;  // 64 threads
    int b = bs / S_, s = bs % S_;
    const float* qr = q + (size_t)bs*INNER_;
    const float* kr = k + (size_t)bs*INNER_;
    const float* vr = v + (size_t)bs*INNER_;
    float dots[8];
    #pragma unroll
    for (int g=0; g<8; ++g) dots[g]=0.f;
    for (int c = lane; c < INNER_; c += 64) {
        float qv = qr[c], kv = kr[c], vv = vr[c];
        #pragma unroll
        for (int g=0; g<4; ++g) {
            dots[g]   += qv*Wig[g*768+c] + kv*Wig[g*768+256+c] + vv*Wig[g*768+512+c];
            dots[4+g] += qv*Wfg[g*768+c] + kv*Wfg[g*768+256+c] + vv*Wfg[g*768+512+c];
        }
    }
    #pragma unroll
    for (int off=32; off>0; off>>=1)
        #pragma unroll
        for (int g=0; g<8; ++g) dots[g] += __shfl_down(dots[g], off, 64);
    if (lane == 0) {
        #pragma unroll
        for (int g=0; g<4; ++g) {
            igp[((size_t)b*NH_+g)*S_ + s] = dots[g]   + big[g];
            fgp[((size_t)b*NH_+g)*S_ + s] = dots[4+g] + bfg[g];
        }
    }
}

// ---------------- mLSTM decay precompute: lc, a = ig - lc, prefix-max(a) ----------------
__global__ void mlstm_scan_pre(const float* __restrict__ igp, const float* __restrict__ fgp,
                               float* __restrict__ lc, float* __restrict__ av,
                               float* __restrict__ mx) {
    int bh = blockIdx.x; int t = threadIdx.x;  // 1024 threads
    __shared__ float buf[2][1024];
    float ls = flogsig(fgp[(size_t)bh*S_ + t]);
    int cur = 0;
    buf[0][t] = ls; __syncthreads();
    for (int off=1; off<1024; off<<=1) {
        float x2 = buf[cur][t];
        if (t >= off) x2 += buf[cur][t-off];
        buf[cur^1][t] = x2; cur ^= 1; __syncthreads();
    }
    float lcv = buf[cur][t];
    lc[(size_t)bh*S_+t] = lcv;
    float a = igp[(size_t)bh*S_+t] - lcv;
    av[(size_t)bh*S_+t] = a;
    __syncthreads();
    cur = 0; buf[0][t] = a; __syncthreads();
    for (int off=1; off<1024; off<<=1) {
        float x2 = buf[cur][t];
        if (t >= off) x2 = fmaxf(x2, buf[cur][t-off]);
        buf[cur^1][t] = x2; cur ^= 1; __syncthreads();
    }
    mx[(size_t)bh*S_+t] = buf[cur][t];
}

// ---------------- mLSTM attention: tiled flash-style, 64 q-rows per block ----------------
__global__ __launch_bounds__(256) void mlstm_attn_tiled(
        const float* __restrict__ q, const float* __restrict__ k,
        const float* __restrict__ v, const float* __restrict__ lc,
        const float* __restrict__ av, const float* __restrict__ mx,
        float* __restrict__ hc) {
    int bid = blockIdx.x;
    int stile = 15 - (bid & 15);        // big tiles dispatch first (load balance)
    int bh = bid >> 4;
    int hh = bh & 3, b = bh >> 2;
    int s0 = stile << 6;
    int tid = threadIdx.x;
    int wid = tid >> 6, lane = tid & 63;
    int wy = wid >> 1, wx = wid & 1;
    int sg = lane >> 3, tg = lane & 7;

    __shared__ float qs[64*68];
    __shared__ float kst[64*68];   // K tile, then overwritten with P tile
    __shared__ float vtT[64*68];   // V tile transposed
    __shared__ float avt[64], maxsL[64], normL[64], rsumL[128];

    const size_t bhS = (size_t)bh * S_;
    {
        int r = tid >> 2, c0 = (tid & 3) << 4;
        const float* qg = q + ((size_t)(b*S_) + s0 + r)*INNER_ + hh*64;
        #pragma unroll
        for (int i = 0; i < 4; ++i) {
            float4 t4 = *(const float4*)(qg + c0 + 4*i);
            float4 w4; w4.x=t4.x*0.125f; w4.y=t4.y*0.125f; w4.z=t4.z*0.125f; w4.w=t4.w*0.125f;
            *(float4*)(&qs[r*68 + c0 + 4*i]) = w4;
        }
        if (tid < 64) maxsL[tid] = lc[bhS + s0 + tid] + mx[bhS + s0 + tid];
    }
    float msv[4];
    #pragma unroll
    for (int i = 0; i < 4; ++i)
        msv[i] = mx[bhS + s0 + 32*wy + 8*i + sg];

    float O[4][4];
    float rsAcc[4];
    #pragma unroll
    for (int i = 0; i < 4; ++i) {
        rsAcc[i] = 0.f;
        #pragma unroll
        for (int j = 0; j < 4; ++j) O[i][j] = 0.f;
    }

    for (int t0 = 0; t0 <= s0; t0 += 64) {
        __syncthreads();
        {
            int r = tid >> 2, c0 = (tid & 3) << 4;
            const float* kg = k + ((size_t)(b*S_) + t0 + r)*INNER_ + hh*64;
            const float* vg = v + ((size_t)(b*S_) + t0 + r)*INNER_ + hh*64;
            #pragma unroll
            for (int i = 0; i < 4; ++i) {
                *(float4*)(&kst[r*68 + c0 + 4*i]) = *(const float4*)(kg + c0 + 4*i);
                float4 v4 = *(const float4*)(vg + c0 + 4*i);
                int dc = c0 + 4*i;
                vtT[(dc+0)*68 + r] = v4.x;
                vtT[(dc+1)*68 + r] = v4.y;
                vtT[(dc+2)*68 + r] = v4.z;
                vtT[(dc+3)*68 + r] = v4.w;
            }
            if (tid < 64) avt[tid] = av[bhS + t0 + tid];
        }
        __syncthreads();
        float dot[4][4];
        #pragma unroll
        for (int i = 0; i < 4; ++i)
            #pragma unroll
            for (int j = 0; j < 4; ++j) dot[i][j] = 0.f;
        {
            const float* qrow = &qs[(32*wy + sg)*68];
            const float* krow = &kst[(32*wx + tg)*68];
            for (int d = 0; d < 64; d += 4) {
                float4 a0 = *(const float4*)(qrow + 0*544 + d);
                float4 a1 = *(const float4*)(qrow + 1*544 + d);
                float4 a2 = *(const float4*)(qrow + 2*544 + d);
                float4 a3 = *(const float4*)(qrow + 3*544 + d);
                float4 b0 = *(const float4*)(krow + 0*544 + d);
                float4 b1 = *(const float4*)(krow + 1*544 + d);
                float4 b2 = *(const float4*)(krow + 2*544 + d);
                float4 b3 = *(const float4*)(krow + 3*544 + d);
                float4 A[4] = {a0,a1,a2,a3}, Bv[4] = {b0,b1,b2,b3};
                #pragma unroll
                for (int i = 0; i < 4; ++i)
                    #pragma unroll
                    for (int j = 0; j < 4; ++j)
                        dot[i][j] += A[i].x*Bv[j].x + A[i].y*Bv[j].y
                                   + A[i].z*Bv[j].z + A[i].w*Bv[j].w;
            }
        }
        __syncthreads();
        #pragma unroll
        for (int i = 0; i < 4; ++i) {
            int s_loc = 32*wy + 8*i + sg;
            float rp = 0.f;
            #pragma unroll
            for (int j = 0; j < 4; ++j) {
                int t_loc = 32*wx + 8*j + tg;
                bool ok = (t0 + t_loc) <= (s0 + s_loc);
                float p = ok ? dot[i][j]*__expf(avt[t_loc] - msv[i]) : 0.f;
                kst[s_loc*68 + t_loc] = p;
                rp += p;
            }
            rp += __shfl_xor(rp, 1);
            rp += __shfl_xor(rp, 2);
            rp += __shfl_xor(rp, 4);
            rsAcc[i] += rp;
        }
        __syncthreads();
        {
            const float* prow = &kst[(32*wy + sg)*68];
            const float* vrow = &vtT[(32*wx + tg)*68];
            for (int tt = 0; tt < 64; tt += 4) {
                float4 a0 = *(const float4*)(prow + 0*544 + tt);
                float4 a1 = *(const float4*)(prow + 1*544 + tt);
                float4 a2 = *(const float4*)(prow + 2*544 + tt);
                float4 a3 = *(const float4*)(prow + 3*544 + tt);
                float4 b0 = *(const float4*)(vrow + 0*544 + tt);
                float4 b1 = *(const float4*)(vrow + 1*544 + tt);
                float4 b2 = *(const float4*)(vrow + 2*544 + tt);
                float4 b3 = *(const float4*)(vrow + 3*544 + tt);
                float4 A[4] = {a0,a1,a2,a3}, Bv[4] = {b0,b1,b2,b3};
                #pragma unroll
                for (int i = 0; i < 4; ++i)
                    #pragma unroll
                    for (int j = 0; j < 4; ++j)
                        O[i][j] += A[i].x*Bv[j].x + A[i].y*Bv[j].y
                                 + A[i].z*Bv[j].z + A[i].w*Bv[j].w;
            }
        }
    }
    if (tg == 0) {
        #pragma unroll
        for (int i = 0; i < 4; ++i)
            rsumL[wx*64 + 32*wy + 8*i + sg] = rsAcc[i];
    }
    __syncthreads();
    if (tid < 64) {
        float tot = rsumL[tid] + rsumL[64 + tid];
        normL[tid] = fmaxf(fabsf(tot), __expf(-maxsL[tid])) + 1e-6f;
    }
    __syncthreads();
    #pragma unroll
    for (int i = 0; i < 4; ++i) {
        int s_loc = 32*wy + 8*i + sg;
        float inv = 1.0f / normL[s_loc];
        #pragma unroll
        for (int j = 0; j < 4; ++j) {
            int d_loc = 32*wx + 8*j + tg;
            hc[((size_t)(b*S_) + s0 + s_loc)*INNER_ + hh*64 + d_loc] = O[i][j] * inv;
        }
    }
}

// ---------------- mLSTM output: multihead LN (GS=64) + skip + gate ----------------
__global__ void mlstm_out(const float* __restrict__ hc, const float* __restrict__ xc,
                          const float* __restrict__ up, const float* __restrict__ onw,
                          const float* __restrict__ skip, float* __restrict__ hs) {
    int row = blockIdx.x; int c = threadIdx.x;  // 256 threads
    float v = hc[(size_t)row*INNER_ + c];
    __shared__ float s1[256], s2[256];
    s1[c]=v; s2[c]=v*v; __syncthreads();
    int li = c & 63;
    for (int off=32; off>0; off>>=1){
        if (li < off){ s1[c]+=s1[c+off]; s2[c]+=s2[c+off]; }
        __syncthreads();
    }
    int base = c & ~63;
    float mu = s1[base]*(1.f/64.f);
    float var = s2[base]*(1.f/64.f) - mu*mu;
    float ht = (v-mu)*rsqrtf(var+1e-5f)*onw[c];
    float z = up[(size_t)row*512 + 256 + c];
    hs[(size_t)row*INNER_ + c] = (ht + skip[c]*xc[(size_t)row*INNER_+c]) * (z*fsigm(z));
}

// ---------------- sLSTM scan: ONE WAVE per (b,h), R in regs, readlane bcast ----------------
// Lane l owns raw entries j0=l, j1=l+64. All 64 lanes run the gate math
// unconditionally (lanes>=32 compute garbage, never read). No LDS, no barriers.
__global__ __launch_bounds__(64) void slstm_scan_wave(
        const float* __restrict__ gx, const float* __restrict__ R,
        const float* __restrict__ bb, float* __restrict__ ys) {
    int blk = blockIdx.x; int hh = blk & 3; int b = blk >> 2;
    int l = threadIdx.x;  // 0..63
    float Rc0[32], Rc1[32];
    #pragma unroll
    for (int d = 0; d < 32; ++d) {
        Rc0[d] = R[(size_t)(hh*32 + d)*128 + l];
        Rc1[d] = R[(size_t)(hh*32 + d)*128 + l + 64];
    }
    float bj0 = bb[hh*128 + l], bj1 = bb[hh*128 + l + 64];
    float cst = 0.f, nst = 0.f, mst = 0.f, y = 0.f;
    const float* gbase = gx + (size_t)(b*S_)*512 + hh*128;
    float* ybase = ys + (size_t)(b*S_)*128 + hh*32;
    float ga[4], gb[4];
    #pragma unroll
    for (int u = 0; u < 4; ++u) {
        ga[u] = gbase[(size_t)u*512 + l];
        gb[u] = gbase[(size_t)u*512 + l + 64];
    }
    for (int t = 0; t < S_; t += 4) {
        float gna[4], gnb[4];
        #pragma unroll
        for (int u = 0; u < 4; ++u) {
            int tn = t + 4 + u;
            size_t off = (size_t)(tn < S_ ? tn : 0) * 512;
            gna[u] = gbase[off + l];
            gnb[u] = gbase[off + l + 64];
        }
        #pragma unroll
        for (int u = 0; u < 4; ++u) {
            float r0 = ga[u] + bj0;
            float r1 = gb[u] + bj1;
            #pragma unroll
            for (int d = 0; d < 32; ++d) {
                float yd = __int_as_float(__builtin_amdgcn_readlane(__float_as_int(y), d));
                r0 += yd * Rc0[d];
                r1 += yd * Rc1[d];
            }
            // lanes<32: r0=iraw[e], r1=zraw[e]; lanes>=32: r0=fraw, r1=oraw
            float fo0 = __shfl_xor(r0, 32, 64);
            float fo1 = __shfl_xor(r1, 32, 64);
            int t_abs = t + u;
            float iraw = r0, zraw = r1, fraw = fo0, oraw = fo1;
            float lfm = mst + flogsig(fraw);
            float mnew = (t_abs == 0) ? iraw : fmaxf(iraw, lfm);
            float og = fsigm(oraw);
            float igv = __expf(iraw - mnew), fgv = __expf(lfm - mnew);
            cst = fgv*cst + igv*ftanh(zraw);
            nst = fgv*nst + igv;
            mst = mnew;
            y = og*cst*frcp(nst);
            if (l < 32) ybase[(size_t)t_abs*128 + l] = y;
        }
        #pragma unroll
        for (int u = 0; u < 4; ++u) { ga[u] = gna[u]; gb[u] = gnb[u]; }
    }
}

// ---------------- sLSTM out: h += mh_ln(ys; GS=32) * gnw ----------------
__global__ void slstm_addnorm(const float* __restrict__ ys, const float* __restrict__ w,
                              float* __restrict__ h) {
    int row = blockIdx.x; int c = threadIdx.x;  // 128
    float v = ys[(size_t)row*128 + c];
    __shared__ float s1[128], s2[128];
    s1[c]=v; s2[c]=v*v; __syncthreads();
    int li = c & 31;
    for (int off=16; off>0; off>>=1){
        if (li < off){ s1[c]+=s1[c+off]; s2[c]+=s2[c+off]; }
        __syncthreads();
    }
    int base = c & ~31;
    float mu = s1[base]*(1.f/32.f);
    float var = s2[base]*(1.f/32.f) - mu*mu;
    h[(size_t)row*128 + c] += (v-mu)*rsqrtf(var+1e-5f)*w[c];
}

// ---------------- FFN activation: gelu(g) * u2 ----------------
__global__ void ffn_act(const float* __restrict__ u, float* __restrict__ act) {
    int idx = blockIdx.x*blockDim.x + threadIdx.x;
    int total = MROWS_*192;
    if (idx >= total) return;
    int j = idx % 192; int m = idx / 192;
    float g  = u[(size_t)m*384 + j];
    float u2 = u[(size_t)m*384 + 192 + j];
    float ge = 0.5f*g*(1.0f + erff(g*0.70710678118f));
    act[(size_t)m*192 + j] = ge*u2;
}

// ---------------- Final FC on last token ----------------
__global__ void final_fc(const float* __restrict__ hp, const float* __restrict__ fcW,
                         const float* __restrict__ fcb, float* __restrict__ out) {
    int b = blockIdx.x; int lane = threadIdx.x;  // 64
    const float* r = hp + ((size_t)b*S_ + (S_-1))*128;
    float acc = r[lane]*fcW[lane] + r[lane+64]*fcW[lane+64];
    #pragma unroll
    for (int off=32; off>0; off>>=1) acc += __shfl_down(acc, off, 64);
    if (lane == 0) out[b] = acc + fcb[0];
}

extern "C" void kernel_launch(void* const* d_in, const int* in_sizes, int n_in,
                              void* d_out, int out_size, void* d_ws, size_t ws_size,
                              hipStream_t stream) {
    const float* x       = (const float*)d_in[0];
    const float* W_in    = (const float*)d_in[1];
    const float* b_in    = (const float*)d_in[2];
    const float* ln0_w   = (const float*)d_in[3];
    const float* m_Wup   = (const float*)d_in[4];
    const float* m_bup   = (const float*)d_in[5];
    const float* m_convk = (const float*)d_in[6];
    const float* m_convb = (const float*)d_in[7];
    const float* m_Wq    = (const float*)d_in[8];
    const float* m_bq    = (const float*)d_in[9];
    const float* m_Wk    = (const float*)d_in[10];
    const float* m_bk    = (const float*)d_in[11];
    const float* m_Wv    = (const float*)d_in[12];
    const float* m_bv    = (const float*)d_in[13];
    const float* m_Wig   = (const float*)d_in[14];
    const float* m_big   = (const float*)d_in[15];
    const float* m_Wfg   = (const float*)d_in[16];
    const float* m_bfg   = (const float*)d_in[17];
    const float* m_onw   = (const float*)d_in[18];
    const float* m_skip  = (const float*)d_in[19];
    const float* m_Wd    = (const float*)d_in[20];
    const float* m_bd    = (const float*)d_in[21];
    const float* ln1_w   = (const float*)d_in[22];
    const float* s_convk = (const float*)d_in[23];
    const float* s_convb = (const float*)d_in[24];
    const float* s_Wi    = (const float*)d_in[25];
    const float* s_Wf    = (const float*)d_in[26];
    const float* s_Wz    = (const float*)d_in[27];
    const float* s_Wo    = (const float*)d_in[28];
    const float* s_R     = (const float*)d_in[29];
    const float* s_b     = (const float*)d_in[30];
    const float* s_gnw   = (const float*)d_in[31];
    const float* ffn_nw  = (const float*)d_in[32];
    const float* f_Wu    = (const float*)d_in[33];
    const float* f_bu    = (const float*)d_in[34];
    const float* f_Wd    = (const float*)d_in[35];
    const float* f_bd    = (const float*)d_in[36];
    const float* post_w  = (const float*)d_in[37];
    const float* fc_W    = (const float*)d_in[38];
    const float* fc_b    = (const float*)d_in[39];
    float* out = (float*)d_out;

    float* W = (float*)d_ws;
    const size_t M1 = 1048576;        // 8192*128
    float* h    = W;                   // 1M
    float* r    = W + 1*M1;            // 1M
    float* up   = W + 2*M1;            // 4M
    float* xc   = W + 6*M1;            // 2M
    float* q    = W + 8*M1;            // 2M
    float* kbuf = W + 10*M1;           // 2M
    float* vbuf = W + 12*M1;           // 2M
    float* hc   = W + 14*M1;           // 2M
    float* igp  = W + 16*M1;
    float* fgp  = igp + 32768;
    float* lc   = fgp + 32768;
    float* av   = lc  + 32768;
    float* mx   = av  + 32768;
    float* hs   = q;
    float* gx   = kbuf;
    float* ys   = hc;
    float* rc   = xc;
    float* u    = up;
    float* act  = q;
    float* hp   = r;

    // 1. h = x @ W_in^T + b_in
    gemm_bias_big<<<dim3(128/64, MROWS_/64), 256, 0, stream>>>(x, W_in, b_in, nullptr, h, MROWS_, 128, F_);
    // 2. r = LN(h)*ln0_w
    ln_kernel<<<MROWS_, 128, 0, stream>>>(h, ln0_w, r);
    // 3. up = r @ m_Wup^T + m_bup
    gemm_bias_big<<<dim3(512/64, MROWS_/64), 256, 0, stream>>>(r, m_Wup, m_bup, nullptr, up, MROWS_, 512, 128);
    // 4. xc = silu(causal_conv(xm))
    conv_silu<<<(MROWS_*256)/256, 256, 0, stream>>>(up, 512, m_convk, m_convb, xc, 256, 256);
    // 5. q,k,v headwise
    headwise4<<<(MROWS_*256)/256, 256, 0, stream>>>(xc, 256, m_Wq, m_bq, q);
    headwise4<<<(MROWS_*256)/256, 256, 0, stream>>>(xc, 256, m_Wk, m_bk, kbuf);
    headwise4<<<(MROWS_*256)/256, 256, 0, stream>>>(up, 512, m_Wv, m_bv, vbuf);
    // 6. ig/fg projections
    gateproj<<<MROWS_, 64, 0, stream>>>(q, kbuf, vbuf, m_Wig, m_big, m_Wfg, m_bfg, igp, fgp);
    // 7. decay precompute
    mlstm_scan_pre<<<B_*NH_, 1024, 0, stream>>>(igp, fgp, lc, av, mx);
    // 8. attention (tiled)
    mlstm_attn_tiled<<<B_*NH_*16, 256, 0, stream>>>(q, kbuf, vbuf, lc, av, mx, hc);
    // 9. multihead LN + skip + gate
    mlstm_out<<<MROWS_, 256, 0, stream>>>(hc, xc, up, m_onw, m_skip, hs);
    // 10. h += hs @ m_Wd^T + m_bd
    gemm_bias_big<<<dim3(128/64, MROWS_/64), 256, 0, stream>>>(hs, m_Wd, m_bd, h, h, MROWS_, 128, 256);
    // 11. r = LN(h)*ln1_w
    ln_kernel<<<MROWS_, 128, 0, stream>>>(h, ln1_w, r);
    // 12. rc = silu(causal_conv(r))
    conv_silu<<<(MROWS_*128)/256, 256, 0, stream>>>(r, 128, s_convk, s_convb, rc, 128, 128);
    // 13. sLSTM gates (all 4 in one launch)
    slstm_gates<<<(MROWS_*128)/256, 256, 0, stream>>>(rc, r, s_Wi, s_Wf, s_Wz, s_Wo, gx);
    // 14. sequential scan (single wave per (b,h), no LDS/barriers)
    slstm_scan_wave<<<B_*NH_, 64, 0, stream>>>(gx, s_R, s_b, ys);
    // 15. h += mh_ln(ys)*s_gnw
    slstm_addnorm<<<MROWS_, 128, 0, stream>>>(ys, s_gnw, h);
    // 16. r = LN(h)*ffn_nw
    ln_kernel<<<MROWS_, 128, 0, stream>>>(h, ffn_nw, r);
    // 17. u = r @ f_Wu^T + f_bu
    gemm_bias_big<<<dim3(384/64, MROWS_/64), 256, 0, stream>>>(r, f_Wu, f_bu, nullptr, u, MROWS_, 384, 128);
    // 18. act = gelu(g)*u2
    ffn_act<<<(MROWS_*192)/256, 256, 0, stream>>>(u, act);
    // 19. h += act @ f_Wd^T + f_bd
    gemm_bias_big<<<dim3(128/64, MROWS_/64), 256, 0, stream>>>(act, f_Wd, f_bd, h, h, MROWS_, 128, 192);
    // 20. hp = LN(h)*post_w
    ln_kernel<<<MROWS_, 128, 0, stream>>>(h, post_w, hp);
    // 21. out = hp[:, -1, :] @ fc_W^T + fc_b
    final_fc<<<B_, 64, 0, stream>>>(hp, fc_W, fc_b, out);
    (void)in_sizes; (void)n_in; (void)out_size; (void)ws_size;
}

// Round 6
// 1034.386 us; speedup vs baseline: 5.3107x; 1.4492x over previous
//
#include <hip/hip_runtime.h>
#include <hip/hip_bf16.h>
#include <math.h>

#define B_ 8
#define S_ 1024
#define F_ 75
#define D_ 128
#define INNER_ 256
#define NH_ 4
#define DH_ 64
#define MROWS_ (B_*S_)   // 8192

static __device__ __forceinline__ float frcp(float x){ return __builtin_amdgcn_rcpf(x); }
static __device__ __forceinline__ float fsigm(float x){ return frcp(1.0f + __expf(-x)); }
static __device__ __forceinline__ float flogsig(float x){
    return fminf(x, 0.f) - __logf(1.0f + __expf(-fabsf(x)));
}
static __device__ __forceinline__ float ftanh(float z){
    return 1.0f - 2.0f*frcp(__expf(2.0f*z) + 1.0f);
}

// ---------------- Tiled GEMM: C = A @ W^T + bias (+ res) ----------------
// 64x64 tile, 256 threads = 4 waves in 2x2; 4x4 register micro-tiles strided
// by 8 (conflict-free stride-68 pattern). B-rows loaded once per d-step,
// A-rows streamed — bounded register pressure (no spills).
__global__ __launch_bounds__(256, 2) void gemm_bias_big(
        const float* __restrict__ A, const float* __restrict__ W,
        const float* __restrict__ bias, const float* __restrict__ res,
        float* __restrict__ C, int M, int N, int K) {
    __shared__ float As[64*68];
    __shared__ float Ws[64*68];
    int tid = threadIdx.x;
    int wid = tid >> 6, lane = tid & 63;
    int wy = wid >> 1, wx = wid & 1;
    int sg = lane >> 3, tg = lane & 7;
    int m0 = blockIdx.y*64, n0 = blockIdx.x*64;
    int r = tid >> 2, c0 = (tid & 3) << 4;
    bool vec = ((K & 3) == 0);
    float acc[4][4];
    #pragma unroll
    for (int i = 0; i < 4; ++i)
        #pragma unroll
        for (int j = 0; j < 4; ++j) acc[i][j] = 0.f;

    for (int k0 = 0; k0 < K; k0 += 64) {
        __syncthreads();
        const float* Ar = A + (size_t)(m0+r)*K + k0;
        const float* Wr = W + (size_t)(n0+r)*K + k0;
        if (vec) {
            #pragma unroll
            for (int i = 0; i < 4; ++i) {
                *(float4*)(&As[r*68 + c0 + 4*i]) = *(const float4*)(Ar + c0 + 4*i);
                *(float4*)(&Ws[r*68 + c0 + 4*i]) = *(const float4*)(Wr + c0 + 4*i);
            }
        } else {
            #pragma unroll
            for (int i = 0; i < 4; ++i)
                #pragma unroll
                for (int e = 0; e < 4; ++e) {
                    int c = c0 + 4*i + e;
                    bool ok = (k0 + c) < K;
                    As[r*68 + c] = ok ? Ar[c] : 0.f;
                    Ws[r*68 + c] = ok ? Wr[c] : 0.f;
                }
        }
        __syncthreads();
        const float* arow = &As[(32*wy + sg)*68];
        const float* brow = &Ws[(32*wx + tg)*68];
        #pragma unroll 2
        for (int d = 0; d < 64; d += 4) {
            float4 b0 = *(const float4*)(brow + 0*544 + d);
            float4 b1 = *(const float4*)(brow + 1*544 + d);
            float4 b2 = *(const float4*)(brow + 2*544 + d);
            float4 b3 = *(const float4*)(brow + 3*544 + d);
            #pragma unroll
            for (int i = 0; i < 4; ++i) {
                float4 a = *(const float4*)(arow + i*544 + d);
                acc[i][0] += a.x*b0.x + a.y*b0.y + a.z*b0.z + a.w*b0.w;
                acc[i][1] += a.x*b1.x + a.y*b1.y + a.z*b1.z + a.w*b1.w;
                acc[i][2] += a.x*b2.x + a.y*b2.y + a.z*b2.z + a.w*b2.w;
                acc[i][3] += a.x*b3.x + a.y*b3.y + a.z*b3.z + a.w*b3.w;
            }
        }
    }
    #pragma unroll
    for (int i = 0; i < 4; ++i) {
        int m = m0 + 32*wy + 8*i + sg;
        #pragma unroll
        for (int j = 0; j < 4; ++j) {
            int n = n0 + 32*wx + 8*j + tg;
            float v = acc[i][j] + bias[n];
            if (res) v += res[(size_t)m*N + n];
            C[(size_t)m*N + n] = v;
        }
    }
}

// ---------------- Plain LayerNorm over D=128 ----------------
__global__ void ln_kernel(const float* __restrict__ X, const float* __restrict__ w,
                          float* __restrict__ Y) {
    int row = blockIdx.x, t = threadIdx.x;  // 128 threads
    float v = X[(size_t)row*128 + t];
    __shared__ float s1[128], s2[128];
    s1[t]=v; s2[t]=v*v; __syncthreads();
    for (int off=64; off>0; off>>=1){
        if (t<off){ s1[t]+=s1[t+off]; s2[t]+=s2[t+off]; }
        __syncthreads();
    }
    float mu = s1[0]*(1.f/128.f);
    float var = s2[0]*(1.f/128.f) - mu*mu;
    Y[(size_t)row*128 + t] = (v-mu)*rsqrtf(var+1e-5f)*w[t];
}

// ---------------- Causal depthwise conv (K=4) + SiLU ----------------
__global__ void conv_silu(const float* __restrict__ X, int ldx,
                          const float* __restrict__ kw, const float* __restrict__ kb,
                          float* __restrict__ Y, int ldy, int C) {
    int idx = blockIdx.x*blockDim.x + threadIdx.x;
    int total = MROWS_*C;
    if (idx >= total) return;
    int c = idx % C; int bs = idx / C;
    int s = bs % S_; int b = bs / S_;
    float acc = kb[c];
    #pragma unroll
    for (int i = 0; i < 4; ++i) {
        int sp = s - 3 + i;
        if (sp >= 0) acc += X[((size_t)b*S_+sp)*ldx + c] * kw[c*4+i];
    }
    Y[((size_t)b*S_+s)*ldy + c] = acc * fsigm(acc);
}

// ---------------- Headwise block-diagonal proj (mLSTM q/k/v, HS=4) ----------------
__global__ void headwise4(const float* __restrict__ X, int ldx,
                          const float* __restrict__ W, const float* __restrict__ bias,
                          float* __restrict__ Y) {
    int idx = blockIdx.x*blockDim.x + threadIdx.x;
    int total = MROWS_*INNER_;
    if (idx >= total) return;
    int co = idx % INNER_; int bs = idx / INNER_;
    int h = co >> 2, o = co & 3;
    const float* Wh = W + ((size_t)h*4 + o)*4;
    const float* xr = X + (size_t)bs*ldx + h*4;
    float acc = bias[co];
    #pragma unroll
    for (int i = 0; i < 4; ++i) acc += xr[i]*Wh[i];
    Y[(size_t)bs*INNER_ + co] = acc;
}

// ---------------- sLSTM all-4-gates headwise (HS=32) ----------------
__global__ void slstm_gates(const float* __restrict__ rc, const float* __restrict__ r,
                            const float* __restrict__ Wi, const float* __restrict__ Wf,
                            const float* __restrict__ Wz, const float* __restrict__ Wo,
                            float* __restrict__ GX) {
    int idx = blockIdx.x*blockDim.x + threadIdx.x;
    int total = MROWS_*128;
    if (idx >= total) return;
    int co = idx % 128; int bs = idx / 128;
    int h = co >> 5, o = co & 31;
    size_t wb = ((size_t)h*32 + o)*32;
    const float* xc_ = rc + (size_t)bs*128 + h*32;
    const float* xr_ = r  + (size_t)bs*128 + h*32;
    float di=0.f, df=0.f, dz=0.f, doo=0.f;
    #pragma unroll
    for (int i = 0; i < 32; ++i) {
        float a = xc_[i], c = xr_[i];
        di  += a*Wi[wb+i];
        df  += a*Wf[wb+i];
        dz  += c*Wz[wb+i];
        doo += c*Wo[wb+i];
    }
    float* g = GX + (size_t)bs*512 + h*128 + o;
    g[0]  = di;
    g[32] = df;
    g[64] = dz;
    g[96] = doo;
}

// ---------------- ig/fg gate projection over concat(q,k,v) ----------------
__global__ void gateproj(const float* __restrict__ q, const float* __restrict__ k,
                         const float* __restrict__ v,
                         const float* __restrict__ Wig, const float* __restrict__ big,
                         const float* __restrict__ Wfg, const float* __restrict__ bfg,
                         float* __restrict__ igp, float* __restrict__ fgp) {
    int bs = blockIdx.x; int lane = threadIdx.x;  // 64 threads
    int b = bs / S_, s = bs % S_;
    const float* qr = q + (size_t)bs*INNER_;
    const float* kr = k + (size_t)bs*INNER_;
    const float* vr = v + (size_t)bs*INNER_;
    float dots[8];
    #pragma unroll
    for (int g=0; g<8; ++g) dots[g]=0.f;
    for (int c = lane; c < INNER_; c += 64) {
        float qv = qr[c], kv = kr[c], vv = vr[c];
        #pragma unroll
        for (int g=0; g<4; ++g) {
            dots[g]   += qv*Wig[g*768+c] + kv*Wig[g*768+256+c] + vv*Wig[g*768+512+c];
            dots[4+g] += qv*Wfg[g*768+c] + kv*Wfg[g*768+256+c] + vv*Wfg[g*768+512+c];
        }
    }
    #pragma unroll
    for (int off=32; off>0; off>>=1)
        #pragma unroll
        for (int g=0; g<8; ++g) dots[g] += __shfl_down(dots[g], off, 64);
    if (lane == 0) {
        #pragma unroll
        for (int g=0; g<4; ++g) {
            igp[((size_t)b*NH_+g)*S_ + s] = dots[g]   + big[g];
            fgp[((size_t)b*NH_+g)*S_ + s] = dots[4+g] + bfg[g];
        }
    }
}

// ---------------- mLSTM decay precompute: lc, a = ig - lc, prefix-max(a) ----------------
__global__ void mlstm_scan_pre(const float* __restrict__ igp, const float* __restrict__ fgp,
                               float* __restrict__ lc, float* __restrict__ av,
                               float* __restrict__ mx) {
    int bh = blockIdx.x; int t = threadIdx.x;  // 1024 threads
    __shared__ float buf[2][1024];
    float ls = flogsig(fgp[(size_t)bh*S_ + t]);
    int cur = 0;
    buf[0][t] = ls; __syncthreads();
    for (int off=1; off<1024; off<<=1) {
        float x2 = buf[cur][t];
        if (t >= off) x2 += buf[cur][t-off];
        buf[cur^1][t] = x2; cur ^= 1; __syncthreads();
    }
    float lcv = buf[cur][t];
    lc[(size_t)bh*S_+t] = lcv;
    float a = igp[(size_t)bh*S_+t] - lcv;
    av[(size_t)bh*S_+t] = a;
    __syncthreads();
    cur = 0; buf[0][t] = a; __syncthreads();
    for (int off=1; off<1024; off<<=1) {
        float x2 = buf[cur][t];
        if (t >= off) x2 = fmaxf(x2, buf[cur][t-off]);
        buf[cur^1][t] = x2; cur ^= 1; __syncthreads();
    }
    mx[(size_t)bh*S_+t] = buf[cur][t];
}

// ---------------- mLSTM attention: tiled flash-style, 64 q-rows per block ----------------
// Register-pressure-bounded inner GEMMs: B-rows loaded once, A-rows streamed,
// unroll capped at 2 so the scheduler cannot hoist 16 iterations of LDS loads.
__global__ __launch_bounds__(256, 2) void mlstm_attn_tiled(
        const float* __restrict__ q, const float* __restrict__ k,
        const float* __restrict__ v, const float* __restrict__ lc,
        const float* __restrict__ av, const float* __restrict__ mx,
        float* __restrict__ hc) {
    int bid = blockIdx.x;
    int stile = 15 - (bid & 15);        // big tiles dispatch first (load balance)
    int bh = bid >> 4;
    int hh = bh & 3, b = bh >> 2;
    int s0 = stile << 6;
    int tid = threadIdx.x;
    int wid = tid >> 6, lane = tid & 63;
    int wy = wid >> 1, wx = wid & 1;
    int sg = lane >> 3, tg = lane & 7;

    __shared__ float qs[64*68];
    __shared__ float kst[64*68];   // K tile, then overwritten with P tile
    __shared__ float vtT[64*68];   // V tile transposed
    __shared__ float avt[64], maxsL[64], normL[64], rsumL[128];

    const size_t bhS = (size_t)bh * S_;
    {
        int r = tid >> 2, c0 = (tid & 3) << 4;
        const float* qg = q + ((size_t)(b*S_) + s0 + r)*INNER_ + hh*64;
        #pragma unroll
        for (int i = 0; i < 4; ++i) {
            float4 t4 = *(const float4*)(qg + c0 + 4*i);
            float4 w4; w4.x=t4.x*0.125f; w4.y=t4.y*0.125f; w4.z=t4.z*0.125f; w4.w=t4.w*0.125f;
            *(float4*)(&qs[r*68 + c0 + 4*i]) = w4;
        }
        if (tid < 64) maxsL[tid] = lc[bhS + s0 + tid] + mx[bhS + s0 + tid];
    }
    float msv[4];
    #pragma unroll
    for (int i = 0; i < 4; ++i)
        msv[i] = mx[bhS + s0 + 32*wy + 8*i + sg];

    float O[4][4];
    float rsAcc[4];
    #pragma unroll
    for (int i = 0; i < 4; ++i) {
        rsAcc[i] = 0.f;
        #pragma unroll
        for (int j = 0; j < 4; ++j) O[i][j] = 0.f;
    }

    for (int t0 = 0; t0 <= s0; t0 += 64) {
        __syncthreads();
        {
            int r = tid >> 2, c0 = (tid & 3) << 4;
            const float* kg = k + ((size_t)(b*S_) + t0 + r)*INNER_ + hh*64;
            const float* vg = v + ((size_t)(b*S_) + t0 + r)*INNER_ + hh*64;
            #pragma unroll
            for (int i = 0; i < 4; ++i) {
                *(float4*)(&kst[r*68 + c0 + 4*i]) = *(const float4*)(kg + c0 + 4*i);
                float4 v4 = *(const float4*)(vg + c0 + 4*i);
                int dc = c0 + 4*i;
                vtT[(dc+0)*68 + r] = v4.x;
                vtT[(dc+1)*68 + r] = v4.y;
                vtT[(dc+2)*68 + r] = v4.z;
                vtT[(dc+3)*68 + r] = v4.w;
            }
            if (tid < 64) avt[tid] = av[bhS + t0 + tid];
        }
        __syncthreads();
        float dot[4][4];
        #pragma unroll
        for (int i = 0; i < 4; ++i)
            #pragma unroll
            for (int j = 0; j < 4; ++j) dot[i][j] = 0.f;
        {
            const float* qrow = &qs[(32*wy + sg)*68];
            const float* krow = &kst[(32*wx + tg)*68];
            #pragma unroll 2
            for (int d = 0; d < 64; d += 4) {
                float4 b0 = *(const float4*)(krow + 0*544 + d);
                float4 b1 = *(const float4*)(krow + 1*544 + d);
                float4 b2 = *(const float4*)(krow + 2*544 + d);
                float4 b3 = *(const float4*)(krow + 3*544 + d);
                #pragma unroll
                for (int i = 0; i < 4; ++i) {
                    float4 a = *(const float4*)(qrow + i*544 + d);
                    dot[i][0] += a.x*b0.x + a.y*b0.y + a.z*b0.z + a.w*b0.w;
                    dot[i][1] += a.x*b1.x + a.y*b1.y + a.z*b1.z + a.w*b1.w;
                    dot[i][2] += a.x*b2.x + a.y*b2.y + a.z*b2.z + a.w*b2.w;
                    dot[i][3] += a.x*b3.x + a.y*b3.y + a.z*b3.z + a.w*b3.w;
                }
            }
        }
        __syncthreads();
        #pragma unroll
        for (int i = 0; i < 4; ++i) {
            int s_loc = 32*wy + 8*i + sg;
            float rp = 0.f;
            #pragma unroll
            for (int j = 0; j < 4; ++j) {
                int t_loc = 32*wx + 8*j + tg;
                bool ok = (t0 + t_loc) <= (s0 + s_loc);
                float p = ok ? dot[i][j]*__expf(avt[t_loc] - msv[i]) : 0.f;
                kst[s_loc*68 + t_loc] = p;
                rp += p;
            }
            rp += __shfl_xor(rp, 1);
            rp += __shfl_xor(rp, 2);
            rp += __shfl_xor(rp, 4);
            rsAcc[i] += rp;
        }
        __syncthreads();
        {
            const float* prow = &kst[(32*wy + sg)*68];
            const float* vrow = &vtT[(32*wx + tg)*68];
            #pragma unroll 2
            for (int tt = 0; tt < 64; tt += 4) {
                float4 b0 = *(const float4*)(vrow + 0*544 + tt);
                float4 b1 = *(const float4*)(vrow + 1*544 + tt);
                float4 b2 = *(const float4*)(vrow + 2*544 + tt);
                float4 b3 = *(const float4*)(vrow + 3*544 + tt);
                #pragma unroll
                for (int i = 0; i < 4; ++i) {
                    float4 a = *(const float4*)(prow + i*544 + tt);
                    O[i][0] += a.x*b0.x + a.y*b0.y + a.z*b0.z + a.w*b0.w;
                    O[i][1] += a.x*b1.x + a.y*b1.y + a.z*b1.z + a.w*b1.w;
                    O[i][2] += a.x*b2.x + a.y*b2.y + a.z*b2.z + a.w*b2.w;
                    O[i][3] += a.x*b3.x + a.y*b3.y + a.z*b3.z + a.w*b3.w;
                }
            }
        }
    }
    if (tg == 0) {
        #pragma unroll
        for (int i = 0; i < 4; ++i)
            rsumL[wx*64 + 32*wy + 8*i + sg] = rsAcc[i];
    }
    __syncthreads();
    if (tid < 64) {
        float tot = rsumL[tid] + rsumL[64 + tid];
        normL[tid] = fmaxf(fabsf(tot), __expf(-maxsL[tid])) + 1e-6f;
    }
    __syncthreads();
    #pragma unroll
    for (int i = 0; i < 4; ++i) {
        int s_loc = 32*wy + 8*i + sg;
        float inv = 1.0f / normL[s_loc];
        #pragma unroll
        for (int j = 0; j < 4; ++j) {
            int d_loc = 32*wx + 8*j + tg;
            hc[((size_t)(b*S_) + s0 + s_loc)*INNER_ + hh*64 + d_loc] = O[i][j] * inv;
        }
    }
}

// ---------------- mLSTM output: multihead LN (GS=64) + skip + gate ----------------
__global__ void mlstm_out(const float* __restrict__ hc, const float* __restrict__ xc,
                          const float* __restrict__ up, const float* __restrict__ onw,
                          const float* __restrict__ skip, float* __restrict__ hs) {
    int row = blockIdx.x; int c = threadIdx.x;  // 256 threads
    float v = hc[(size_t)row*INNER_ + c];
    __shared__ float s1[256], s2[256];
    s1[c]=v; s2[c]=v*v; __syncthreads();
    int li = c & 63;
    for (int off=32; off>0; off>>=1){
        if (li < off){ s1[c]+=s1[c+off]; s2[c]+=s2[c+off]; }
        __syncthreads();
    }
    int base = c & ~63;
    float mu = s1[base]*(1.f/64.f);
    float var = s2[base]*(1.f/64.f) - mu*mu;
    float ht = (v-mu)*rsqrtf(var+1e-5f)*onw[c];
    float z = up[(size_t)row*512 + 256 + c];
    hs[(size_t)row*INNER_ + c] = (ht + skip[c]*xc[(size_t)row*INNER_+c]) * (z*fsigm(z));
}

// ---------------- sLSTM scan: ONE WAVE per (b,h), R in regs, readlane bcast ----------------
__global__ __launch_bounds__(64) void slstm_scan_wave(
        const float* __restrict__ gx, const float* __restrict__ R,
        const float* __restrict__ bb, float* __restrict__ ys) {
    int blk = blockIdx.x; int hh = blk & 3; int b = blk >> 2;
    int l = threadIdx.x;  // 0..63
    float Rc0[32], Rc1[32];
    #pragma unroll
    for (int d = 0; d < 32; ++d) {
        Rc0[d] = R[(size_t)(hh*32 + d)*128 + l];
        Rc1[d] = R[(size_t)(hh*32 + d)*128 + l + 64];
    }
    float bj0 = bb[hh*128 + l], bj1 = bb[hh*128 + l + 64];
    float cst = 0.f, nst = 0.f, mst = 0.f, y = 0.f;
    const float* gbase = gx + (size_t)(b*S_)*512 + hh*128;
    float* ybase = ys + (size_t)(b*S_)*128 + hh*32;
    float ga[4], gb[4];
    #pragma unroll
    for (int u = 0; u < 4; ++u) {
        ga[u] = gbase[(size_t)u*512 + l];
        gb[u] = gbase[(size_t)u*512 + l + 64];
    }
    for (int t = 0; t < S_; t += 4) {
        float gna[4], gnb[4];
        #pragma unroll
        for (int u = 0; u < 4; ++u) {
            int tn = t + 4 + u;
            size_t off = (size_t)(tn < S_ ? tn : 0) * 512;
            gna[u] = gbase[off + l];
            gnb[u] = gbase[off + l + 64];
        }
        #pragma unroll
        for (int u = 0; u < 4; ++u) {
            float r0 = ga[u] + bj0;
            float r1 = gb[u] + bj1;
            #pragma unroll
            for (int d = 0; d < 32; ++d) {
                float yd = __int_as_float(__builtin_amdgcn_readlane(__float_as_int(y), d));
                r0 += yd * Rc0[d];
                r1 += yd * Rc1[d];
            }
            float fo0 = __shfl_xor(r0, 32, 64);
            float fo1 = __shfl_xor(r1, 32, 64);
            int t_abs = t + u;
            float iraw = r0, zraw = r1, fraw = fo0, oraw = fo1;
            float lfm = mst + flogsig(fraw);
            float mnew = (t_abs == 0) ? iraw : fmaxf(iraw, lfm);
            float og = fsigm(oraw);
            float igv = __expf(iraw - mnew), fgv = __expf(lfm - mnew);
            cst = fgv*cst + igv*ftanh(zraw);
            nst = fgv*nst + igv;
            mst = mnew;
            y = og*cst*frcp(nst);
            if (l < 32) ybase[(size_t)t_abs*128 + l] = y;
        }
        #pragma unroll
        for (int u = 0; u < 4; ++u) { ga[u] = gna[u]; gb[u] = gnb[u]; }
    }
}

// ---------------- sLSTM out: h += mh_ln(ys; GS=32) * gnw ----------------
__global__ void slstm_addnorm(const float* __restrict__ ys, const float* __restrict__ w,
                              float* __restrict__ h) {
    int row = blockIdx.x; int c = threadIdx.x;  // 128
    float v = ys[(size_t)row*128 + c];
    __shared__ float s1[128], s2[128];
    s1[c]=v; s2[c]=v*v; __syncthreads();
    int li = c & 31;
    for (int off=16; off>0; off>>=1){
        if (li < off){ s1[c]+=s1[c+off]; s2[c]+=s2[c+off]; }
        __syncthreads();
    }
    int base = c & ~31;
    float mu = s1[base]*(1.f/32.f);
    float var = s2[base]*(1.f/32.f) - mu*mu;
    h[(size_t)row*128 + c] += (v-mu)*rsqrtf(var+1e-5f)*w[c];
}

// ---------------- FFN activation: gelu(g) * u2 ----------------
__global__ void ffn_act(const float* __restrict__ u, float* __restrict__ act) {
    int idx = blockIdx.x*blockDim.x + threadIdx.x;
    int total = MROWS_*192;
    if (idx >= total) return;
    int j = idx % 192; int m = idx / 192;
    float g  = u[(size_t)m*384 + j];
    float u2 = u[(size_t)m*384 + 192 + j];
    float ge = 0.5f*g*(1.0f + erff(g*0.70710678118f));
    act[(size_t)m*192 + j] = ge*u2;
}

// ---------------- Final FC on last token ----------------
__global__ void final_fc(const float* __restrict__ hp, const float* __restrict__ fcW,
                         const float* __restrict__ fcb, float* __restrict__ out) {
    int b = blockIdx.x; int lane = threadIdx.x;  // 64
    const float* r = hp + ((size_t)b*S_ + (S_-1))*128;
    float acc = r[lane]*fcW[lane] + r[lane+64]*fcW[lane+64];
    #pragma unroll
    for (int off=32; off>0; off>>=1) acc += __shfl_down(acc, off, 64);
    if (lane == 0) out[b] = acc + fcb[0];
}

extern "C" void kernel_launch(void* const* d_in, const int* in_sizes, int n_in,
                              void* d_out, int out_size, void* d_ws, size_t ws_size,
                              hipStream_t stream) {
    const float* x       = (const float*)d_in[0];
    const float* W_in    = (const float*)d_in[1];
    const float* b_in    = (const float*)d_in[2];
    const float* ln0_w   = (const float*)d_in[3];
    const float* m_Wup   = (const float*)d_in[4];
    const float* m_bup   = (const float*)d_in[5];
    const float* m_convk = (const float*)d_in[6];
    const float* m_convb = (const float*)d_in[7];
    const float* m_Wq    = (const float*)d_in[8];
    const float* m_bq    = (const float*)d_in[9];
    const float* m_Wk    = (const float*)d_in[10];
    const float* m_bk    = (const float*)d_in[11];
    const float* m_Wv    = (const float*)d_in[12];
    const float* m_bv    = (const float*)d_in[13];
    const float* m_Wig   = (const float*)d_in[14];
    const float* m_big   = (const float*)d_in[15];
    const float* m_Wfg   = (const float*)d_in[16];
    const float* m_bfg   = (const float*)d_in[17];
    const float* m_onw   = (const float*)d_in[18];
    const float* m_skip  = (const float*)d_in[19];
    const float* m_Wd    = (const float*)d_in[20];
    const float* m_bd    = (const float*)d_in[21];
    const float* ln1_w   = (const float*)d_in[22];
    const float* s_convk = (const float*)d_in[23];
    const float* s_convb = (const float*)d_in[24];
    const float* s_Wi    = (const float*)d_in[25];
    const float* s_Wf    = (const float*)d_in[26];
    const float* s_Wz    = (const float*)d_in[27];
    const float* s_Wo    = (const float*)d_in[28];
    const float* s_R     = (const float*)d_in[29];
    const float* s_b     = (const float*)d_in[30];
    const float* s_gnw   = (const float*)d_in[31];
    const float* ffn_nw  = (const float*)d_in[32];
    const float* f_Wu    = (const float*)d_in[33];
    const float* f_bu    = (const float*)d_in[34];
    const float* f_Wd    = (const float*)d_in[35];
    const float* f_bd    = (const float*)d_in[36];
    const float* post_w  = (const float*)d_in[37];
    const float* fc_W    = (const float*)d_in[38];
    const float* fc_b    = (const float*)d_in[39];
    float* out = (float*)d_out;

    float* W = (float*)d_ws;
    const size_t M1 = 1048576;        // 8192*128
    float* h    = W;                   // 1M
    float* r    = W + 1*M1;            // 1M
    float* up   = W + 2*M1;            // 4M
    float* xc   = W + 6*M1;            // 2M
    float* q    = W + 8*M1;            // 2M
    float* kbuf = W + 10*M1;           // 2M
    float* vbuf = W + 12*M1;           // 2M
    float* hc   = W + 14*M1;           // 2M
    float* igp  = W + 16*M1;
    float* fgp  = igp + 32768;
    float* lc   = fgp + 32768;
    float* av   = lc  + 32768;
    float* mx   = av  + 32768;
    float* hs   = q;
    float* gx   = kbuf;
    float* ys   = hc;
    float* rc   = xc;
    float* u    = up;
    float* act  = q;
    float* hp   = r;

    // 1. h = x @ W_in^T + b_in
    gemm_bias_big<<<dim3(128/64, MROWS_/64), 256, 0, stream>>>(x, W_in, b_in, nullptr, h, MROWS_, 128, F_);
    // 2. r = LN(h)*ln0_w
    ln_kernel<<<MROWS_, 128, 0, stream>>>(h, ln0_w, r);
    // 3. up = r @ m_Wup^T + m_bup
    gemm_bias_big<<<dim3(512/64, MROWS_/64), 256, 0, stream>>>(r, m_Wup, m_bup, nullptr, up, MROWS_, 512, 128);
    // 4. xc = silu(causal_conv(xm))
    conv_silu<<<(MROWS_*256)/256, 256, 0, stream>>>(up, 512, m_convk, m_convb, xc, 256, 256);
    // 5. q,k,v headwise
    headwise4<<<(MROWS_*256)/256, 256, 0, stream>>>(xc, 256, m_Wq, m_bq, q);
    headwise4<<<(MROWS_*256)/256, 256, 0, stream>>>(xc, 256, m_Wk, m_bk, kbuf);
    headwise4<<<(MROWS_*256)/256, 256, 0, stream>>>(up, 512, m_Wv, m_bv, vbuf);
    // 6. ig/fg projections
    gateproj<<<MROWS_, 64, 0, stream>>>(q, kbuf, vbuf, m_Wig, m_big, m_Wfg, m_bfg, igp, fgp);
    // 7. decay precompute
    mlstm_scan_pre<<<B_*NH_, 1024, 0, stream>>>(igp, fgp, lc, av, mx);
    // 8. attention (tiled)
    mlstm_attn_tiled<<<B_*NH_*16, 256, 0, stream>>>(q, kbuf, vbuf, lc, av, mx, hc);
    // 9. multihead LN + skip + gate
    mlstm_out<<<MROWS_, 256, 0, stream>>>(hc, xc, up, m_onw, m_skip, hs);
    // 10. h += hs @ m_Wd^T + m_bd
    gemm_bias_big<<<dim3(128/64, MROWS_/64), 256, 0, stream>>>(hs, m_Wd, m_bd, h, h, MROWS_, 128, 256);
    // 11. r = LN(h)*ln1_w
    ln_kernel<<<MROWS_, 128, 0, stream>>>(h, ln1_w, r);
    // 12. rc = silu(causal_conv(r))
    conv_silu<<<(MROWS_*128)/256, 256, 0, stream>>>(r, 128, s_convk, s_convb, rc, 128, 128);
    // 13. sLSTM gates (all 4 in one launch)
    slstm_gates<<<(MROWS_*128)/256, 256, 0, stream>>>(rc, r, s_Wi, s_Wf, s_Wz, s_Wo, gx);
    // 14. sequential scan (single wave per (b,h), no LDS/barriers)
    slstm_scan_wave<<<B_*NH_, 64, 0, stream>>>(gx, s_R, s_b, ys);
    // 15. h += mh_ln(ys)*s_gnw
    slstm_addnorm<<<MROWS_, 128, 0, stream>>>(ys, s_gnw, h);
    // 16. r = LN(h)*ffn_nw
    ln_kernel<<<MROWS_, 128, 0, stream>>>(h, ffn_nw, r);
    // 17. u = r @ f_Wu^T + f_bu
    gemm_bias_big<<<dim3(384/64, MROWS_/64), 256, 0, stream>>>(r, f_Wu, f_bu, nullptr, u, MROWS_, 384, 128);
    // 18. act = gelu(g)*u2
    ffn_act<<<(MROWS_*192)/256, 256, 0, stream>>>(u, act);
    // 19. h += act @ f_Wd^T + f_bd
    gemm_bias_big<<<dim3(128/64, MROWS_/64), 256, 0, stream>>>(act, f_Wd, f_bd, h, h, MROWS_, 128, 192);
    // 20. hp = LN(h)*post_w
    ln_kernel<<<MROWS_, 128, 0, stream>>>(h, post_w, hp);
    // 21. out = hp[:, -1, :] @ fc_W^T + fc_b
    final_fc<<<B_, 64, 0, stream>>>(hp, fc_W, fc_b, out);
    (void)in_sizes; (void)n_in; (void)out_size; (void)ws_size;
}